// Round 1
// baseline (2141.626 us; speedup 1.0000x reference)
//
#include <hip/hip_runtime.h>
#include <stdint.h>

typedef unsigned int u32;
typedef unsigned long long u64;

#define NB 4
#define CIN 512
#define HH 64
#define WWID 64
#define NPOS 4096          // 64*64
#define NANCH 36864        // NPOS*9
#define NPRE 6000
#define NPOST 300
#define CAP 6144
#define NEG_INF_F (-1e30f)

// monotonic float->uint mapping (ascending)
__device__ __forceinline__ u32 fsort(float f) {
    u32 u = __float_as_uint(f);
    return (u & 0x80000000u) ? ~u : (u | 0x80000000u);
}
__device__ __forceinline__ float funsort(u32 u) {
    return (u & 0x80000000u) ? __uint_as_float(u ^ 0x80000000u) : __uint_as_float(~u);
}

// ---------------- init: zero the compact counters ----------------
__global__ void init_k(u32* cnt) {
    if (threadIdx.x < 8) cnt[threadIdx.x] = 0u;
}

// ---------------- transpose conv1 weights to [ci][kh][kw][co] ----------------
__global__ void twc_k(const float* __restrict__ w, float* __restrict__ wt) {
    int i = blockIdx.x * 256 + threadIdx.x;
    if (i >= 512 * 512 * 9) return;
    int co = i / 4608;
    int rem = i - co * 4608;
    int ci = rem / 9;
    int k = rem - ci * 9;
    wt[(ci * 9 + k) * 512 + co] = w[i];
}

// ---------------- pack 1x1 weights to [ci][64] (ch<18 score, 18..53 loc) ----------------
__global__ void tw1_k(const float* __restrict__ sw, const float* __restrict__ lw,
                      float* __restrict__ wt1) {
    int i = blockIdx.x * 256 + threadIdx.x;
    if (i >= 512 * 64) return;
    int ci = i >> 6;
    int ch = i & 63;
    float v = 0.f;
    if (ch < 18) v = sw[ch * 512 + ci];
    else if (ch < 54) v = lw[(ch - 18) * 512 + ci];
    wt1[i] = v;
}

// ---------------- conv1: 3x3 512->512 + bias + relu ----------------
// grid (8 co-blocks, 64 h, 4 n); block 256 = 4 waves; wave handles 16 cos, lane = w
__global__ __launch_bounds__(256, 4) void conv1_k(const float* __restrict__ x,
                                                  const float* __restrict__ wt,
                                                  const float* __restrict__ bias,
                                                  float* __restrict__ feat) {
    const int tid = threadIdx.x;
    const int lane = tid & 63;
    const int wv = __builtin_amdgcn_readfirstlane(tid >> 6);
    const int cb = blockIdx.x;
    const int h = blockIdx.y;
    const int n = blockIdx.z;
    const int co_base = cb * 64 + wv * 16;

    __shared__ float xs[16 * 3 * 66];

    float acc[16];
#pragma unroll
    for (int i = 0; i < 16; i++) acc[i] = 0.f;

    for (int ch = 0; ch < 32; ++ch) {
        __syncthreads();
        for (int s = tid; s < 16 * 3 * 66; s += 256) {
            int ci = s / 198;
            int rem = s - ci * 198;
            int r = rem / 66;
            int c = rem - r * 66;
            int gr = h + r - 1;
            int gc = c - 1;
            float v = 0.f;
            if ((unsigned)gr < 64u && (unsigned)gc < 64u)
                v = x[(((size_t)n * 512 + (ch * 16 + ci)) * 64 + gr) * 64 + gc];
            xs[s] = v;
        }
        __syncthreads();

#pragma unroll 2
        for (int ci = 0; ci < 16; ++ci) {
            int cig = ch * 16 + ci;
#pragma unroll
            for (int kh = 0; kh < 3; ++kh) {
                const float* xrow = &xs[(ci * 3 + kh) * 66];
                float xv0 = xrow[lane];
                float xv1 = xrow[lane + 1];
                float xv2 = xrow[lane + 2];
                const float* wbase = wt + ((size_t)(cig * 3 + kh) * 3) * 512 + co_base;
#pragma unroll
                for (int kw = 0; kw < 3; ++kw) {
                    float xv = (kw == 0) ? xv0 : ((kw == 1) ? xv1 : xv2);
                    const float4* wp = (const float4*)(wbase + kw * 512);
#pragma unroll
                    for (int q = 0; q < 4; q++) {
                        float4 w4 = wp[q];
                        acc[q * 4 + 0] = fmaf(w4.x, xv, acc[q * 4 + 0]);
                        acc[q * 4 + 1] = fmaf(w4.y, xv, acc[q * 4 + 1]);
                        acc[q * 4 + 2] = fmaf(w4.z, xv, acc[q * 4 + 2]);
                        acc[q * 4 + 3] = fmaf(w4.w, xv, acc[q * 4 + 3]);
                    }
                }
            }
        }
    }

#pragma unroll
    for (int c = 0; c < 16; c++) {
        float v = acc[c] + bias[co_base + c];
        v = v > 0.f ? v : 0.f;
        feat[(((size_t)n * 512 + (co_base + c)) * 64 + h) * 64 + lane] = v;
    }
}

// ---------------- head: 1x1 convs + softmax-fg + loc2bbox + clip + valid ----------------
// grid (64 rows, 4 n), block 64 (lane = w)
__global__ __launch_bounds__(64) void head_k(const float* __restrict__ feat,
                                             const float* __restrict__ wt1,
                                             const float* __restrict__ sb,
                                             const float* __restrict__ lb,
                                             const int* __restrict__ img_h,
                                             const int* __restrict__ img_w,
                                             float* __restrict__ out_loc,   // out + 0
                                             float* __restrict__ out_sc,    // out + 589824
                                             float* __restrict__ boxes,
                                             float* __restrict__ scf) {
    const int lane = threadIdx.x;
    const int row = blockIdx.x;
    const int n = blockIdx.y;

    float acc[56];
#pragma unroll
    for (int i = 0; i < 56; i++) acc[i] = 0.f;

    for (int ci = 0; ci < 512; ++ci) {
        float f = feat[(((size_t)n * 512 + ci) * 64 + row) * 64 + lane];
        const float4* wp = (const float4*)(wt1 + ci * 64);
#pragma unroll
        for (int q = 0; q < 14; q++) {
            float4 w4 = wp[q];
            acc[q * 4 + 0] = fmaf(f, w4.x, acc[q * 4 + 0]);
            acc[q * 4 + 1] = fmaf(f, w4.y, acc[q * 4 + 1]);
            acc[q * 4 + 2] = fmaf(f, w4.z, acc[q * 4 + 2]);
            acc[q * 4 + 3] = fmaf(f, w4.w, acc[q * 4 + 3]);
        }
    }

    float ihf = (float)img_h[0];
    float iwf = (float)img_w[0];
    int p = row * 64 + lane;
    size_t base = (size_t)n * NANCH + (size_t)p * 9;
    float sy = 16.f * (float)row;
    float sx = 16.f * (float)lane;
    const float rat[3] = {0.5f, 1.f, 2.f};
    const float scl[3] = {8.f, 16.f, 32.f};

#pragma unroll
    for (int a = 0; a < 9; a++) {
        int r = a / 3, s = a % 3;
        float hh = 16.f * scl[s] * sqrtf(rat[r]);
        float wwv = 16.f * scl[s] * sqrtf(1.f / rat[r]);
        float ab0 = 8.f - 0.5f * hh, ab1 = 8.f - 0.5f * wwv;
        float ab2 = 8.f + 0.5f * hh, ab3 = 8.f + 0.5f * wwv;
        float a0 = sy + ab0, a1c = sx + ab1, a2 = sy + ab2, a3 = sx + ab3;

        float s0 = acc[a * 2 + 0] + sb[a * 2 + 0];
        float s1 = acc[a * 2 + 1] + sb[a * 2 + 1];
        ((float2*)out_sc)[base + a] = make_float2(s0, s1);
        float m = fmaxf(s0, s1);
        float e0 = expf(s0 - m), e1 = expf(s1 - m);
        float fg = e1 / (e0 + e1);

        float dy = acc[18 + a * 4 + 0] + lb[a * 4 + 0];
        float dx = acc[18 + a * 4 + 1] + lb[a * 4 + 1];
        float dh = acc[18 + a * 4 + 2] + lb[a * 4 + 2];
        float dw = acc[18 + a * 4 + 3] + lb[a * 4 + 3];
        ((float4*)out_loc)[base + a] = make_float4(dy, dx, dh, dw);

        float h_ = a2 - a0, w_ = a3 - a1c;
        float cy = a0 + 0.5f * h_, cx = a1c + 0.5f * w_;
        float ncy = dy * h_ + cy, ncx = dx * w_ + cx;
        float nh = expf(dh) * h_, nw = expf(dw) * w_;
        float y1 = ncy - 0.5f * nh, x1 = ncx - 0.5f * nw;
        float y2 = ncy + 0.5f * nh, x2 = ncx + 0.5f * nw;
        y1 = fminf(fmaxf(y1, 0.f), ihf);
        x1 = fminf(fmaxf(x1, 0.f), iwf);
        y2 = fminf(fmaxf(y2, 0.f), ihf);
        x2 = fminf(fmaxf(x2, 0.f), iwf);
        float hs = y2 - y1, wsz = x2 - x1;
        bool valid = (hs >= 16.f) && (wsz >= 16.f);
        ((float4*)boxes)[base + a] = make_float4(y1, x1, y2, x2);
        scf[base + a] = valid ? fg : NEG_INF_F;
    }
}

// ---------------- anchors output ----------------
__global__ void anch_k(float* __restrict__ out_anchor) {
    int i = blockIdx.x * 256 + threadIdx.x;
    if (i >= NANCH) return;
    int p = i / 9, a = i - p * 9;
    int y = p / 64, xq = p - y * 64;
    int r = a / 3, s = a - r * 3;
    const float rat[3] = {0.5f, 1.f, 2.f};
    const float scl[3] = {8.f, 16.f, 32.f};
    float hh = 16.f * scl[s] * sqrtf(rat[r]);
    float wwv = 16.f * scl[s] * sqrtf(1.f / rat[r]);
    float ab0 = 8.f - 0.5f * hh, ab1 = 8.f - 0.5f * wwv;
    float ab2 = 8.f + 0.5f * hh, ab3 = 8.f + 0.5f * wwv;
    float sy = 16.f * (float)y, sx = 16.f * (float)xq;
    ((float4*)out_anchor)[i] = make_float4(sy + ab0, sx + ab1, sy + ab2, sx + ab3);
}

// ---------------- radix select: exact rank-6000 value per batch ----------------
__global__ __launch_bounds__(1024) void radix_k(const float* __restrict__ scf, u32* __restrict__ uT) {
    const int b = blockIdx.x;
    const int tid = threadIdx.x;
    const float* s = scf + (size_t)b * NANCH;
    __shared__ u32 hist[256];
    __shared__ u32 sel_prefix;
    __shared__ int sel_rank;
    if (tid == 0) { sel_prefix = 0u; sel_rank = NPRE; }
    __syncthreads();
    for (int p = 3; p >= 0; --p) {
        for (int i = tid; i < 256; i += 1024) hist[i] = 0u;
        __syncthreads();
        u32 prefix = sel_prefix;
        u32 highmask = (p == 3) ? 0u : (0xFFFFFFFFu << ((p + 1) * 8));
        for (int i = tid; i < NANCH; i += 1024) {
            u32 u = fsort(s[i]);
            if ((u & highmask) == prefix)
                atomicAdd(&hist[(u >> (p * 8)) & 255], 1u);
        }
        __syncthreads();
        if (tid == 0) {
            int r = sel_rank;
            u32 accum = 0;
            int bsel = 0;
            for (int bb = 255; bb >= 0; --bb) {
                accum += hist[bb];
                if ((int)accum >= r) {
                    bsel = bb;
                    sel_rank = r - (int)(accum - hist[bb]);
                    break;
                }
            }
            sel_prefix = prefix | ((u32)bsel << (p * 8));
        }
        __syncthreads();
    }
    if (tid == 0) uT[b] = sel_prefix;
}

// ---------------- compact: gather valid entries with score >= threshold ----------------
__global__ void compact_k(const float* __restrict__ scf, const u32* __restrict__ uT,
                          u32* __restrict__ cnt, u32* __restrict__ cidx) {
    int b = blockIdx.y;
    int i = blockIdx.x * 256 + threadIdx.x;
    float s = scf[(size_t)b * NANCH + i];
    u32 u = fsort(s);
    if (u >= uT[b] && s > -5e29f) {
        u32 p = atomicAdd(&cnt[b], 1u);
        if (p < CAP) cidx[(size_t)b * CAP + p] = (u32)i;
    }
}

// ---------------- NMS: reference argmax loop over compacted set ----------------
// one block (1024 threads) per batch; 6 entries per thread in registers
__global__ __launch_bounds__(1024) void nms_k(const float* __restrict__ boxes,
                                              const float* __restrict__ scf,
                                              const u32* __restrict__ cnt,
                                              const u32* __restrict__ cidx,
                                              float* __restrict__ out_rois) {
    const int b = blockIdx.x;
    const int tid = threadIdx.x;
    int count = (int)cnt[b];
    if (count > CAP) count = CAP;

    const float* Bx = boxes + (size_t)b * NANCH * 4;
    const float* Sc = scf + (size_t)b * NANCH;
    float* rois = out_rois + (size_t)b * NPOST * 4;

    u64 key[6];
    float4 box[6];
#pragma unroll
    for (int k = 0; k < 6; k++) {
        int s = k * 1024 + tid;
        key[k] = 0ull;
        box[k] = make_float4(0.f, 0.f, 0.f, 0.f);
        if (s < count) {
            u32 idx = cidx[(size_t)b * CAP + s];
            float sv = Sc[idx];
            u32 u = fsort(sv);
            key[k] = ((u64)u << 32) | (u64)(0xFFFFFFFFu - idx);
            box[k] = ((const float4*)Bx)[idx];
        }
    }

    __shared__ u64 red[16];
    __shared__ u64 winkey;
    __shared__ float4 winbox;

    int it = 0;
    for (; it < NPOST; ++it) {
        u64 mk = key[0];
#pragma unroll
        for (int k = 1; k < 6; k++) mk = (key[k] > mk) ? key[k] : mk;
#pragma unroll
        for (int off = 32; off; off >>= 1) {
            u64 o = __shfl_xor(mk, off, 64);
            mk = (o > mk) ? o : mk;
        }
        if ((tid & 63) == 0) red[tid >> 6] = mk;
        __syncthreads();
        if (tid == 0) {
            u64 w = red[0];
            for (int q = 1; q < 16; q++) w = (red[q] > w) ? red[q] : w;
            winkey = w;
        }
        __syncthreads();
        u64 wk = winkey;
        float wscore = funsort((u32)(wk >> 32));
        if (!(wscore > -5e29f)) break;

#pragma unroll
        for (int k = 0; k < 6; k++) {
            if (key[k] == wk) {
                winbox = box[k];
                ((float4*)rois)[it] = box[k];
                key[k] = 0ull;
            }
        }
        __syncthreads();
        float4 wb = winbox;
        float a1 = (wb.z - wb.x) * (wb.w - wb.y);
#pragma unroll
        for (int k = 0; k < 6; k++) {
            if (key[k] != 0ull) {
                float ty = fmaxf(wb.x, box[k].x);
                float tx = fmaxf(wb.y, box[k].y);
                float by = fminf(wb.z, box[k].z);
                float bx = fminf(wb.w, box[k].w);
                float dyv = fmaxf(by - ty, 0.f);
                float dxv = fmaxf(bx - tx, 0.f);
                float inter = dyv * dxv;
                float a2 = (box[k].z - box[k].x) * (box[k].w - box[k].y);
                float iou = inter / fmaxf(a1 + a2 - inter, 1e-6f);
                if (iou > 0.7f) key[k] = 0ull;
            }
        }
        // next iteration's first barrier orders winbox reads vs rewrites
    }

    for (int q = it * 4 + tid; q < NPOST * 4; q += 1024) rois[q] = 0.f;
}

// ---------------- launch ----------------
extern "C" void kernel_launch(void* const* d_in, const int* in_sizes, int n_in,
                              void* d_out, int out_size, void* d_ws, size_t ws_size,
                              hipStream_t stream) {
    const float* x  = (const float*)d_in[0];
    const float* w1 = (const float*)d_in[1];
    const float* b1 = (const float*)d_in[2];
    const float* sw = (const float*)d_in[3];
    const float* sb = (const float*)d_in[4];
    const float* lw = (const float*)d_in[5];
    const float* lb = (const float*)d_in[6];
    const int* ih   = (const int*)d_in[7];
    const int* iw   = (const int*)d_in[8];
    float* out = (float*)d_out;

    char* ws = (char*)d_ws;
    float* wt    = (float*)(ws);                    // 512*9*512 f = 9437184 B
    float* wt1   = (float*)(ws + 9437184);          // 512*64 f   = 131072 B
    float* feat  = (float*)(ws + 9568256);          // 4*512*4096 = 33554432 B
    float* boxes = (float*)(ws + 43122688);         // 4*36864*4  = 2359296 B
    float* scf   = (float*)(ws + 45481984);         // 4*36864    = 589824 B
    u32* uT      = (u32*)(ws + 46071808);           // 16 B (+pad)
    u32* cnt     = (u32*)(ws + 46072064);           // 32 B (+pad)
    u32* cidx    = (u32*)(ws + 46072320);           // 4*6144*4 = 98304 B -> end ~46.2 MB

    float* out_loc = out;                  // 589824 floats
    float* out_sc  = out + 589824;         // 294912 floats
    float* out_roi = out + 884736;         // 4800 floats
    float* out_anc = out + 889536;         // 147456 floats

    hipLaunchKernelGGL(init_k, dim3(1), dim3(64), 0, stream, cnt);
    hipLaunchKernelGGL(twc_k, dim3((512 * 512 * 9 + 255) / 256), dim3(256), 0, stream, w1, wt);
    hipLaunchKernelGGL(tw1_k, dim3(128), dim3(256), 0, stream, sw, lw, wt1);
    hipLaunchKernelGGL(conv1_k, dim3(8, 64, 4), dim3(256), 0, stream, x, wt, b1, feat);
    hipLaunchKernelGGL(head_k, dim3(64, 4), dim3(64), 0, stream, feat, wt1, sb, lb, ih, iw,
                       out_loc, out_sc, boxes, scf);
    hipLaunchKernelGGL(anch_k, dim3(144), dim3(256), 0, stream, out_anc);
    hipLaunchKernelGGL(radix_k, dim3(4), dim3(1024), 0, stream, scf, uT);
    hipLaunchKernelGGL(compact_k, dim3(144, 4), dim3(256), 0, stream, scf, uT, cnt, cidx);
    hipLaunchKernelGGL(nms_k, dim3(4), dim3(1024), 0, stream, boxes, scf, cnt, cidx, out_roi);
}

// Round 2
// 1760.907 us; speedup vs baseline: 1.2162x; 1.2162x over previous
//
#include <hip/hip_runtime.h>
#include <stdint.h>

typedef unsigned int u32;
typedef unsigned long long u64;
typedef unsigned short ushort_t;

#define NANCH 36864        // 4096*9
#define NPRE 6000
#define NPOST 300
#define CAP 6144
#define NEG_INF_F (-1e30f)

typedef __attribute__((ext_vector_type(8))) __bf16 bf8_t;
typedef __attribute__((ext_vector_type(8))) unsigned short us8_t;
typedef __attribute__((ext_vector_type(16))) float f32x16;

union pun8 { us8_t u; bf8_t b; };

// monotonic float->uint mapping (ascending)
__device__ __forceinline__ u32 fsort(float f) {
    u32 u = __float_as_uint(f);
    return (u & 0x80000000u) ? ~u : (u | 0x80000000u);
}
__device__ __forceinline__ float funsort(u32 u) {
    return (u & 0x80000000u) ? __uint_as_float(u ^ 0x80000000u) : __uint_as_float(~u);
}

// RNE float -> bf16 bits, and exact bf16 bits -> float
__device__ __forceinline__ unsigned short f2bf(float f) {
    u32 u = __float_as_uint(f);
    u32 r = (u + 0x7FFFu + ((u >> 16) & 1u)) >> 16;
    return (unsigned short)r;
}
__device__ __forceinline__ float bf2f(unsigned short s) {
    return __uint_as_float(((u32)s) << 16);
}

// ---------------- init: zero the compact counters ----------------
__global__ void init_k(u32* cnt) {
    if (threadIdx.x < 8) cnt[threadIdx.x] = 0u;
}

// ---------------- weight prepack: fp32 OIHW -> bf16x3 split, MFMA-A-fragment order
// Wp layout (us8 units): [sa(3)][t(9)][kc(32)][cot(16)][lane(64)] ; each us8 = 8 consecutive ci (j)
// A-frag (32x32x16): lane l holds A[row=co = l&31][k=ci = (l>>5)*8 + j]
__global__ void wpack_k(const float* __restrict__ w, ushort_t* __restrict__ Wp) {
    int T = blockIdx.x * 256 + threadIdx.x;   // 0..32767
    if (T >= 32768) return;
    int lane31 = T & 31;
    int cot    = (T >> 5) & 15;
    int khalf  = (T >> 9) & 1;
    int kc     = T >> 10;                      // 0..31
    int co  = cot * 32 + lane31;
    int ci0 = kc * 16 + khalf * 8;
    int lane = lane31 + khalf * 32;
    const float* wr = w + (size_t)co * 4608 + (size_t)ci0 * 9;
    us8_t* P = (us8_t*)Wp;
    const size_t sa_stride = (size_t)9 * 32 * 16 * 64;   // us8 units per split
#pragma unroll
    for (int t = 0; t < 9; ++t) {
        us8_t vh, vm, vl;
#pragma unroll
        for (int j = 0; j < 8; ++j) {
            float v = wr[j * 9 + t];
            unsigned short h = f2bf(v); float r1 = v - bf2f(h);
            unsigned short m = f2bf(r1); float r2 = r1 - bf2f(m);
            vh[j] = h; vm[j] = m; vl[j] = f2bf(r2);
        }
        size_t base = ((((size_t)t) * 32 + kc) * 16 + cot) * 64 + lane;
        P[base] = vh;
        P[base + sa_stride] = vm;
        P[base + 2 * sa_stride] = vl;
    }
}

// ---------------- pack 1x1 weights to [ci][64] (ch<18 score, 18..53 loc) ----------------
__global__ void tw1_k(const float* __restrict__ sw, const float* __restrict__ lw,
                      float* __restrict__ wt1) {
    int i = blockIdx.x * 256 + threadIdx.x;
    if (i >= 512 * 64) return;
    int ci = i >> 6;
    int ch = i & 63;
    float v = 0.f;
    if (ch < 18) v = sw[ch * 512 + ci];
    else if (ch < 54) v = lw[(ch - 18) * 512 + ci];
    wt1[i] = v;
}

// ---------------- conv1 via bf16x6 MFMA ----------------
// pass handles n in {2*pass, 2*pass+1}. Grid 256 blocks x 256 threads (4 waves).
// Block tile: 128 co (co-quarter coq) x 128 pixels (rows h0,h0+1 of one n, w 0..63).
// Wave wv: pix-tile: r = wv>>1, wb = (wv&1)*32; covers all 128 co as 4 subtiles of 32.
// LDS X tile: per split: [4 rows][66 cols][ci pad 24] ushort; ci-chunk = 16 per K step.
__global__ __launch_bounds__(256, 2) void conv_mfma_k(const float* __restrict__ x,
                                                      const ushort_t* __restrict__ Wp,
                                                      const float* __restrict__ bias,
                                                      float* __restrict__ feat,
                                                      int pass) {
    __shared__ __align__(16) unsigned short xs[3 * 6336];   // 38016 B

    const int bid = blockIdx.x;
    const int xcd = bid & 7, slot = bid >> 3;
    const int coq = xcd >> 1;                      // weight slice pinned per XCD-pair (L2)
    const int g = ((xcd & 1) << 5) | slot;         // 0..63
    const int n2 = g >> 5;                         // 0..1
    const int hp = g & 31;
    const int n = pass * 2 + n2;
    const int h0 = hp * 2;

    const int tid = threadIdx.x;
    const int lane = tid & 63;
    const int wv = tid >> 6;                       // 0..3
    const int r = wv >> 1;                         // pixel row within pair
    const int wb = (wv & 1) * 32;                  // pixel col base
    const int col31 = lane & 31;
    const int halfk = lane >> 5;

    f32x16 acc[4];
#pragma unroll
    for (int q = 0; q < 4; ++q)
#pragma unroll
        for (int i = 0; i < 16; ++i) acc[q][i] = 0.f;

    const us8_t* Pw = (const us8_t*)Wp;
    const size_t sa_stride = (size_t)9 * 32 * 16 * 64;
    static const int sal[6] = {0, 0, 1, 0, 1, 2};
    static const int sbl[6] = {0, 1, 0, 2, 1, 0};

    for (int kc = 0; kc < 32; ++kc) {
        // ---- stage X chunk (ci0..ci0+15) into LDS as 3 bf16 splits ----
        for (int e = tid; e < 528; e += 256) {          // 4 rows * 66 cols * 2 halves
            int half = e & 1;
            int rc = e >> 1;
            int rr = rc / 66;
            int cc = rc - rr * 66;
            int gr = h0 + rr - 1;
            int gc = cc - 1;
            bool inb = ((unsigned)gr < 64u) && ((unsigned)gc < 64u);
            int ci0 = kc * 16 + half * 8;
            const float* xp = x + ((((size_t)n * 512 + ci0) * 64 + gr) * 64 + gc);
            us8_t vh, vm, vl;
#pragma unroll
            for (int j = 0; j < 8; ++j) {
                float v = inb ? xp[(size_t)j * 4096] : 0.f;
                unsigned short h = f2bf(v); float r1 = v - bf2f(h);
                unsigned short m = f2bf(r1); float r2 = r1 - bf2f(m);
                vh[j] = h; vm[j] = m; vl[j] = f2bf(r2);
            }
            int off = (rr * 66 + cc) * 24 + half * 8;
            *(us8_t*)&xs[off] = vh;
            *(us8_t*)&xs[6336 + off] = vm;
            *(us8_t*)&xs[12672 + off] = vl;
        }
        __syncthreads();

#pragma unroll
        for (int t = 0; t < 9; ++t) {
            const int kh = t / 3, kw = t - kh * 3;
            // B fragments (one per split)
            pun8 Bf[3];
            int boff = ((r + kh) * 66 + (wb + col31 + kw)) * 24 + halfk * 8;
#pragma unroll
            for (int sb = 0; sb < 3; ++sb)
                Bf[sb].u = *(const us8_t*)&xs[sb * 6336 + boff];
            // A fragments (3 splits x 4 co-subtiles)
            pun8 Af[3][4];
            size_t abase = (((size_t)t * 32 + kc) * 16 + coq * 4) * 64 + lane;
#pragma unroll
            for (int sa = 0; sa < 3; ++sa)
#pragma unroll
                for (int q = 0; q < 4; ++q)
                    Af[sa][q].u = Pw[sa * sa_stride + abase + (size_t)q * 64];
            // 6 split-pairs x 4 co-subtiles
#pragma unroll
            for (int pp = 0; pp < 6; ++pp) {
                const int sa = sal[pp], sb = sbl[pp];
#pragma unroll
                for (int q = 0; q < 4; ++q)
                    acc[q] = __builtin_amdgcn_mfma_f32_32x32x16_bf16(
                        Af[sa][q].b, Bf[sb].b, acc[q], 0, 0, 0);
            }
        }
        __syncthreads();
    }

    // ---- epilogue: bias + relu, store fp32 feat[n2][co][h][w] ----
#pragma unroll
    for (int q = 0; q < 4; ++q) {
#pragma unroll
        for (int i = 0; i < 16; ++i) {
            int m = (i & 3) + 8 * (i >> 2) + 4 * halfk;
            int co = coq * 128 + q * 32 + m;
            float v = acc[q][i] + bias[co];
            v = v > 0.f ? v : 0.f;
            feat[(((size_t)n2 * 512 + co) * 64 + (h0 + r)) * 64 + (wb + col31)] = v;
        }
    }
}

// ---------------- head: 1x1 convs + softmax-fg + loc2bbox + clip + valid ----------------
// grid (64 rows, 2 n2) per pass, block 64 (lane = w)
__global__ __launch_bounds__(64) void head_k(const float* __restrict__ feat,
                                             const float* __restrict__ wt1,
                                             const float* __restrict__ sb,
                                             const float* __restrict__ lb,
                                             const int* __restrict__ img_h,
                                             const int* __restrict__ img_w,
                                             float* __restrict__ out_loc,
                                             float* __restrict__ out_sc,
                                             float* __restrict__ boxes,
                                             float* __restrict__ scf,
                                             int pass) {
    const int lane = threadIdx.x;
    const int row = blockIdx.x;
    const int n2 = blockIdx.y;
    const int n = pass * 2 + n2;

    float acc[56];
#pragma unroll
    for (int i = 0; i < 56; i++) acc[i] = 0.f;

    for (int ci = 0; ci < 512; ++ci) {
        float f = feat[(((size_t)n2 * 512 + ci) * 64 + row) * 64 + lane];
        const float4* wp = (const float4*)(wt1 + ci * 64);
#pragma unroll
        for (int q = 0; q < 14; q++) {
            float4 w4 = wp[q];
            acc[q * 4 + 0] = fmaf(f, w4.x, acc[q * 4 + 0]);
            acc[q * 4 + 1] = fmaf(f, w4.y, acc[q * 4 + 1]);
            acc[q * 4 + 2] = fmaf(f, w4.z, acc[q * 4 + 2]);
            acc[q * 4 + 3] = fmaf(f, w4.w, acc[q * 4 + 3]);
        }
    }

    float ihf = (float)img_h[0];
    float iwf = (float)img_w[0];
    int p = row * 64 + lane;
    size_t base = (size_t)n * NANCH + (size_t)p * 9;
    float sy = 16.f * (float)row;
    float sx = 16.f * (float)lane;
    const float rat[3] = {0.5f, 1.f, 2.f};
    const float scl[3] = {8.f, 16.f, 32.f};

#pragma unroll
    for (int a = 0; a < 9; a++) {
        int rr = a / 3, s = a % 3;
        float hh = 16.f * scl[s] * sqrtf(rat[rr]);
        float wwv = 16.f * scl[s] * sqrtf(1.f / rat[rr]);
        float ab0 = 8.f - 0.5f * hh, ab1 = 8.f - 0.5f * wwv;
        float ab2 = 8.f + 0.5f * hh, ab3 = 8.f + 0.5f * wwv;
        float a0 = sy + ab0, a1c = sx + ab1, a2 = sy + ab2, a3 = sx + ab3;

        float s0 = acc[a * 2 + 0] + sb[a * 2 + 0];
        float s1 = acc[a * 2 + 1] + sb[a * 2 + 1];
        ((float2*)out_sc)[base + a] = make_float2(s0, s1);
        float m = fmaxf(s0, s1);
        float e0 = expf(s0 - m), e1 = expf(s1 - m);
        float fg = e1 / (e0 + e1);

        float dy = acc[18 + a * 4 + 0] + lb[a * 4 + 0];
        float dx = acc[18 + a * 4 + 1] + lb[a * 4 + 1];
        float dh = acc[18 + a * 4 + 2] + lb[a * 4 + 2];
        float dw = acc[18 + a * 4 + 3] + lb[a * 4 + 3];
        ((float4*)out_loc)[base + a] = make_float4(dy, dx, dh, dw);

        float h_ = a2 - a0, w_ = a3 - a1c;
        float cy = a0 + 0.5f * h_, cx = a1c + 0.5f * w_;
        float ncy = dy * h_ + cy, ncx = dx * w_ + cx;
        float nh = expf(dh) * h_, nw = expf(dw) * w_;
        float y1 = ncy - 0.5f * nh, x1 = ncx - 0.5f * nw;
        float y2 = ncy + 0.5f * nh, x2 = ncx + 0.5f * nw;
        y1 = fminf(fmaxf(y1, 0.f), ihf);
        x1 = fminf(fmaxf(x1, 0.f), iwf);
        y2 = fminf(fmaxf(y2, 0.f), ihf);
        x2 = fminf(fmaxf(x2, 0.f), iwf);
        float hs = y2 - y1, wsz = x2 - x1;
        bool valid = (hs >= 16.f) && (wsz >= 16.f);
        ((float4*)boxes)[base + a] = make_float4(y1, x1, y2, x2);
        scf[base + a] = valid ? fg : NEG_INF_F;
    }
}

// ---------------- anchors output ----------------
__global__ void anch_k(float* __restrict__ out_anchor) {
    int i = blockIdx.x * 256 + threadIdx.x;
    if (i >= NANCH) return;
    int p = i / 9, a = i - p * 9;
    int y = p / 64, xq = p - y * 64;
    int r = a / 3, s = a - r * 3;
    const float rat[3] = {0.5f, 1.f, 2.f};
    const float scl[3] = {8.f, 16.f, 32.f};
    float hh = 16.f * scl[s] * sqrtf(rat[r]);
    float wwv = 16.f * scl[s] * sqrtf(1.f / rat[r]);
    float ab0 = 8.f - 0.5f * hh, ab1 = 8.f - 0.5f * wwv;
    float ab2 = 8.f + 0.5f * hh, ab3 = 8.f + 0.5f * wwv;
    float sy = 16.f * (float)y, sx = 16.f * (float)xq;
    ((float4*)out_anchor)[i] = make_float4(sy + ab0, sx + ab1, sy + ab2, sx + ab3);
}

// ---------------- radix select: exact rank-6000 value per batch ----------------
__global__ __launch_bounds__(1024) void radix_k(const float* __restrict__ scf, u32* __restrict__ uT) {
    const int b = blockIdx.x;
    const int tid = threadIdx.x;
    const float* s = scf + (size_t)b * NANCH;
    __shared__ u32 hist[256];
    __shared__ u32 sel_prefix;
    __shared__ int sel_rank;
    if (tid == 0) { sel_prefix = 0u; sel_rank = NPRE; }
    __syncthreads();
    for (int p = 3; p >= 0; --p) {
        for (int i = tid; i < 256; i += 1024) hist[i] = 0u;
        __syncthreads();
        u32 prefix = sel_prefix;
        u32 highmask = (p == 3) ? 0u : (0xFFFFFFFFu << ((p + 1) * 8));
        for (int i = tid; i < NANCH; i += 1024) {
            u32 u = fsort(s[i]);
            if ((u & highmask) == prefix)
                atomicAdd(&hist[(u >> (p * 8)) & 255], 1u);
        }
        __syncthreads();
        if (tid == 0) {
            int r = sel_rank;
            u32 accum = 0;
            int bsel = 0;
            for (int bb = 255; bb >= 0; --bb) {
                accum += hist[bb];
                if ((int)accum >= r) {
                    bsel = bb;
                    sel_rank = r - (int)(accum - hist[bb]);
                    break;
                }
            }
            sel_prefix = prefix | ((u32)bsel << (p * 8));
        }
        __syncthreads();
    }
    if (tid == 0) uT[b] = sel_prefix;
}

// ---------------- compact: gather valid entries with score >= threshold ----------------
__global__ void compact_k(const float* __restrict__ scf, const u32* __restrict__ uT,
                          u32* __restrict__ cnt, u32* __restrict__ cidx) {
    int b = blockIdx.y;
    int i = blockIdx.x * 256 + threadIdx.x;
    float s = scf[(size_t)b * NANCH + i];
    u32 u = fsort(s);
    if (u >= uT[b] && s > -5e29f) {
        u32 p = atomicAdd(&cnt[b], 1u);
        if (p < CAP) cidx[(size_t)b * CAP + p] = (u32)i;
    }
}

// ---------------- NMS: reference argmax loop over compacted set ----------------
__global__ __launch_bounds__(1024) void nms_k(const float* __restrict__ boxes,
                                              const float* __restrict__ scf,
                                              const u32* __restrict__ cnt,
                                              const u32* __restrict__ cidx,
                                              float* __restrict__ out_rois) {
    const int b = blockIdx.x;
    const int tid = threadIdx.x;
    int count = (int)cnt[b];
    if (count > CAP) count = CAP;

    const float* Bx = boxes + (size_t)b * NANCH * 4;
    const float* Sc = scf + (size_t)b * NANCH;
    float* rois = out_rois + (size_t)b * NPOST * 4;

    u64 key[6];
    float4 box[6];
#pragma unroll
    for (int k = 0; k < 6; k++) {
        int s = k * 1024 + tid;
        key[k] = 0ull;
        box[k] = make_float4(0.f, 0.f, 0.f, 0.f);
        if (s < count) {
            u32 idx = cidx[(size_t)b * CAP + s];
            float sv = Sc[idx];
            u32 u = fsort(sv);
            key[k] = ((u64)u << 32) | (u64)(0xFFFFFFFFu - idx);
            box[k] = ((const float4*)Bx)[idx];
        }
    }

    __shared__ u64 red[16];
    __shared__ u64 winkey;
    __shared__ float4 winbox;

    int it = 0;
    for (; it < NPOST; ++it) {
        u64 mk = key[0];
#pragma unroll
        for (int k = 1; k < 6; k++) mk = (key[k] > mk) ? key[k] : mk;
#pragma unroll
        for (int off = 32; off; off >>= 1) {
            u64 o = __shfl_xor(mk, off, 64);
            mk = (o > mk) ? o : mk;
        }
        if ((tid & 63) == 0) red[tid >> 6] = mk;
        __syncthreads();
        if (tid == 0) {
            u64 w = red[0];
            for (int q = 1; q < 16; q++) w = (red[q] > w) ? red[q] : w;
            winkey = w;
        }
        __syncthreads();
        u64 wk = winkey;
        float wscore = funsort((u32)(wk >> 32));
        if (!(wscore > -5e29f)) break;

#pragma unroll
        for (int k = 0; k < 6; k++) {
            if (key[k] == wk) {
                winbox = box[k];
                ((float4*)rois)[it] = box[k];
                key[k] = 0ull;
            }
        }
        __syncthreads();
        float4 wb = winbox;
        float a1 = (wb.z - wb.x) * (wb.w - wb.y);
#pragma unroll
        for (int k = 0; k < 6; k++) {
            if (key[k] != 0ull) {
                float ty = fmaxf(wb.x, box[k].x);
                float tx = fmaxf(wb.y, box[k].y);
                float by = fminf(wb.z, box[k].z);
                float bx = fminf(wb.w, box[k].w);
                float dyv = fmaxf(by - ty, 0.f);
                float dxv = fmaxf(bx - tx, 0.f);
                float inter = dyv * dxv;
                float a2 = (box[k].z - box[k].x) * (box[k].w - box[k].y);
                float iou = inter / fmaxf(a1 + a2 - inter, 1e-6f);
                if (iou > 0.7f) key[k] = 0ull;
            }
        }
    }

    for (int q = it * 4 + tid; q < NPOST * 4; q += 1024) rois[q] = 0.f;
}

// ---------------- launch ----------------
extern "C" void kernel_launch(void* const* d_in, const int* in_sizes, int n_in,
                              void* d_out, int out_size, void* d_ws, size_t ws_size,
                              hipStream_t stream) {
    const float* x  = (const float*)d_in[0];
    const float* w1 = (const float*)d_in[1];
    const float* b1 = (const float*)d_in[2];
    const float* sw = (const float*)d_in[3];
    const float* sb = (const float*)d_in[4];
    const float* lw = (const float*)d_in[5];
    const float* lb = (const float*)d_in[6];
    const int* ih   = (const int*)d_in[7];
    const int* iw   = (const int*)d_in[8];
    float* out = (float*)d_out;

    char* ws = (char*)d_ws;
    ushort_t* Wp  = (ushort_t*)(ws);                 // 3*9*512*512*2 B = 14155776
    float* wt1    = (float*)(ws + 14155776);         // 131072 B
    float* feat   = (float*)(ws + 14286848);         // 2*512*64*64*4 = 16777216 B
    float* boxes  = (float*)(ws + 31064064);         // 4*36864*16   = 2359296 B
    float* scf    = (float*)(ws + 33423360);         // 4*36864*4    = 589824 B
    u32* uT       = (u32*)(ws + 34013184);
    u32* cnt      = (u32*)(ws + 34013440);
    u32* cidx     = (u32*)(ws + 34013696);           // 98304 B -> end ~34.1 MB

    float* out_loc = out;                  // 589824 floats
    float* out_sc  = out + 589824;         // 294912 floats
    float* out_roi = out + 884736;         // 4800 floats
    float* out_anc = out + 889536;         // 147456 floats

    hipLaunchKernelGGL(init_k, dim3(1), dim3(64), 0, stream, cnt);
    hipLaunchKernelGGL(wpack_k, dim3(128), dim3(256), 0, stream, w1, Wp);
    hipLaunchKernelGGL(tw1_k, dim3(128), dim3(256), 0, stream, sw, lw, wt1);
    hipLaunchKernelGGL(anch_k, dim3(144), dim3(256), 0, stream, out_anc);

    for (int pass = 0; pass < 2; ++pass) {
        hipLaunchKernelGGL(conv_mfma_k, dim3(256), dim3(256), 0, stream, x, Wp, b1, feat, pass);
        hipLaunchKernelGGL(head_k, dim3(64, 2), dim3(64), 0, stream, feat, wt1, sb, lb, ih, iw,
                           out_loc, out_sc, boxes, scf, pass);
    }

    hipLaunchKernelGGL(radix_k, dim3(4), dim3(1024), 0, stream, scf, uT);
    hipLaunchKernelGGL(compact_k, dim3(144, 4), dim3(256), 0, stream, scf, uT, cnt, cidx);
    hipLaunchKernelGGL(nms_k, dim3(4), dim3(1024), 0, stream, boxes, scf, cnt, cidx, out_roi);
}

// Round 4
// 1502.375 us; speedup vs baseline: 1.4255x; 1.1721x over previous
//
#include <hip/hip_runtime.h>
#include <stdint.h>

typedef unsigned int u32;
typedef unsigned long long u64;
typedef unsigned short ushort_t;

#define NANCH 36864        // 4096*9
#define NPRE 6000
#define NPOST 300
#define CAP 6144
#define NKEEP 6000         // exact top-k truncation
#define MROWS 6016         // mask rows padded (94*64)
#define MW 192             // u32 words per mask row (6144 bits)
#define NEG_INF_F (-1e30f)

typedef __attribute__((ext_vector_type(8))) __bf16 bf8_t;
typedef __attribute__((ext_vector_type(8))) unsigned short us8_t;
typedef __attribute__((ext_vector_type(16))) float f32x16;

union pun8 { us8_t u; bf8_t b; };

// monotonic float->uint mapping (ascending)
__device__ __forceinline__ u32 fsort(float f) {
    u32 u = __float_as_uint(f);
    return (u & 0x80000000u) ? ~u : (u | 0x80000000u);
}

// RNE float -> bf16 bits, and exact bf16 bits -> float
__device__ __forceinline__ unsigned short f2bf(float f) {
    u32 u = __float_as_uint(f);
    u32 r = (u + 0x7FFFu + ((u >> 16) & 1u)) >> 16;
    return (unsigned short)r;
}
__device__ __forceinline__ float bf2f(unsigned short s) {
    return __uint_as_float(((u32)s) << 16);
}

// safe ctz: identity for nonzero input; defined (0) for zero (result unused then)
__device__ __forceinline__ int ctz32(u32 x) {
    return __builtin_ctz(x ? x : 1u);
}

// ---------------- init: zero the compact counters ----------------
__global__ void init_k(u32* cnt) {
    if (threadIdx.x < 8) cnt[threadIdx.x] = 0u;
}

// ---------------- weight prepack: fp32 OIHW -> bf16x3 split, MFMA-A-fragment order
__global__ void wpack_k(const float* __restrict__ w, ushort_t* __restrict__ Wp) {
    int T = blockIdx.x * 256 + threadIdx.x;   // 0..32767
    if (T >= 32768) return;
    int lane31 = T & 31;
    int cot    = (T >> 5) & 15;
    int khalf  = (T >> 9) & 1;
    int kc     = T >> 10;                      // 0..31
    int co  = cot * 32 + lane31;
    int ci0 = kc * 16 + khalf * 8;
    int lane = lane31 + khalf * 32;
    const float* wr = w + (size_t)co * 4608 + (size_t)ci0 * 9;
    us8_t* P = (us8_t*)Wp;
    const size_t sa_stride = (size_t)9 * 32 * 16 * 64;   // us8 units per split
#pragma unroll
    for (int t = 0; t < 9; ++t) {
        us8_t vh, vm, vl;
#pragma unroll
        for (int j = 0; j < 8; ++j) {
            float v = wr[j * 9 + t];
            unsigned short h = f2bf(v); float r1 = v - bf2f(h);
            unsigned short m = f2bf(r1); float r2 = r1 - bf2f(m);
            vh[j] = h; vm[j] = m; vl[j] = f2bf(r2);
        }
        size_t base = ((((size_t)t) * 32 + kc) * 16 + cot) * 64 + lane;
        P[base] = vh;
        P[base + sa_stride] = vm;
        P[base + 2 * sa_stride] = vl;
    }
}

// ---------------- pack 1x1 weights to [ci][64] ----------------
__global__ void tw1_k(const float* __restrict__ sw, const float* __restrict__ lw,
                      float* __restrict__ wt1) {
    int i = blockIdx.x * 256 + threadIdx.x;
    if (i >= 512 * 64) return;
    int ci = i >> 6;
    int ch = i & 63;
    float v = 0.f;
    if (ch < 18) v = sw[ch * 512 + ci];
    else if (ch < 54) v = lw[(ch - 18) * 512 + ci];
    wt1[i] = v;
}

// ---------------- conv1 via bf16x6 MFMA ----------------
__global__ __launch_bounds__(256, 2) void conv_mfma_k(const float* __restrict__ x,
                                                      const ushort_t* __restrict__ Wp,
                                                      const float* __restrict__ bias,
                                                      float* __restrict__ feat,
                                                      int pass) {
    __shared__ __align__(16) unsigned short xs[3 * 6336];   // 38016 B

    const int bid = blockIdx.x;
    const int xcd = bid & 7, slot = bid >> 3;
    const int coq = xcd >> 1;
    const int g = ((xcd & 1) << 5) | slot;
    const int n2 = g >> 5;
    const int hp = g & 31;
    const int n = pass * 2 + n2;
    const int h0 = hp * 2;

    const int tid = threadIdx.x;
    const int lane = tid & 63;
    const int wv = tid >> 6;
    const int r = wv >> 1;
    const int wb = (wv & 1) * 32;
    const int col31 = lane & 31;
    const int halfk = lane >> 5;

    f32x16 acc[4];
#pragma unroll
    for (int q = 0; q < 4; ++q)
#pragma unroll
        for (int i = 0; i < 16; ++i) acc[q][i] = 0.f;

    const us8_t* Pw = (const us8_t*)Wp;
    const size_t sa_stride = (size_t)9 * 32 * 16 * 64;
    static const int sal[6] = {0, 0, 1, 0, 1, 2};
    static const int sbl[6] = {0, 1, 0, 2, 1, 0};

    for (int kc = 0; kc < 32; ++kc) {
        for (int e = tid; e < 528; e += 256) {
            int half = e & 1;
            int rc = e >> 1;
            int rr = rc / 66;
            int cc = rc - rr * 66;
            int gr = h0 + rr - 1;
            int gc = cc - 1;
            bool inb = ((unsigned)gr < 64u) && ((unsigned)gc < 64u);
            int ci0 = kc * 16 + half * 8;
            const float* xp = x + ((((size_t)n * 512 + ci0) * 64 + gr) * 64 + gc);
            us8_t vh, vm, vl;
#pragma unroll
            for (int j = 0; j < 8; ++j) {
                float v = inb ? xp[(size_t)j * 4096] : 0.f;
                unsigned short h = f2bf(v); float r1 = v - bf2f(h);
                unsigned short m = f2bf(r1); float r2 = r1 - bf2f(m);
                vh[j] = h; vm[j] = m; vl[j] = f2bf(r2);
            }
            int off = (rr * 66 + cc) * 24 + half * 8;
            *(us8_t*)&xs[off] = vh;
            *(us8_t*)&xs[6336 + off] = vm;
            *(us8_t*)&xs[12672 + off] = vl;
        }
        __syncthreads();

#pragma unroll
        for (int t = 0; t < 9; ++t) {
            const int kh = t / 3, kw = t - kh * 3;
            pun8 Bf[3];
            int boff = ((r + kh) * 66 + (wb + col31 + kw)) * 24 + halfk * 8;
#pragma unroll
            for (int sb = 0; sb < 3; ++sb)
                Bf[sb].u = *(const us8_t*)&xs[sb * 6336 + boff];
            pun8 Af[3][4];
            size_t abase = (((size_t)t * 32 + kc) * 16 + coq * 4) * 64 + lane;
#pragma unroll
            for (int sa = 0; sa < 3; ++sa)
#pragma unroll
                for (int q = 0; q < 4; ++q)
                    Af[sa][q].u = Pw[sa * sa_stride + abase + (size_t)q * 64];
#pragma unroll
            for (int pp = 0; pp < 6; ++pp) {
                const int sa = sal[pp], sb = sbl[pp];
#pragma unroll
                for (int q = 0; q < 4; ++q)
                    acc[q] = __builtin_amdgcn_mfma_f32_32x32x16_bf16(
                        Af[sa][q].b, Bf[sb].b, acc[q], 0, 0, 0);
            }
        }
        __syncthreads();
    }

#pragma unroll
    for (int q = 0; q < 4; ++q) {
#pragma unroll
        for (int i = 0; i < 16; ++i) {
            int m = (i & 3) + 8 * (i >> 2) + 4 * halfk;
            int co = coq * 128 + q * 32 + m;
            float v = acc[q][i] + bias[co];
            v = v > 0.f ? v : 0.f;
            feat[(((size_t)n2 * 512 + co) * 64 + (h0 + r)) * 64 + (wb + col31)] = v;
        }
    }
}

// ---------------- head: 1x1 convs + softmax-fg + loc2bbox + clip + valid ----------------
__global__ __launch_bounds__(64) void head_k(const float* __restrict__ feat,
                                             const float* __restrict__ wt1,
                                             const float* __restrict__ sb,
                                             const float* __restrict__ lb,
                                             const int* __restrict__ img_h,
                                             const int* __restrict__ img_w,
                                             float* __restrict__ out_loc,
                                             float* __restrict__ out_sc,
                                             float* __restrict__ boxes,
                                             float* __restrict__ scf,
                                             int pass) {
    const int lane = threadIdx.x;
    const int row = blockIdx.x;
    const int n2 = blockIdx.y;
    const int n = pass * 2 + n2;

    float acc[56];
#pragma unroll
    for (int i = 0; i < 56; i++) acc[i] = 0.f;

    for (int ci = 0; ci < 512; ++ci) {
        float f = feat[(((size_t)n2 * 512 + ci) * 64 + row) * 64 + lane];
        const float4* wp = (const float4*)(wt1 + ci * 64);
#pragma unroll
        for (int q = 0; q < 14; q++) {
            float4 w4 = wp[q];
            acc[q * 4 + 0] = fmaf(f, w4.x, acc[q * 4 + 0]);
            acc[q * 4 + 1] = fmaf(f, w4.y, acc[q * 4 + 1]);
            acc[q * 4 + 2] = fmaf(f, w4.z, acc[q * 4 + 2]);
            acc[q * 4 + 3] = fmaf(f, w4.w, acc[q * 4 + 3]);
        }
    }

    float ihf = (float)img_h[0];
    float iwf = (float)img_w[0];
    int p = row * 64 + lane;
    size_t base = (size_t)n * NANCH + (size_t)p * 9;
    float sy = 16.f * (float)row;
    float sx = 16.f * (float)lane;
    const float rat[3] = {0.5f, 1.f, 2.f};
    const float scl[3] = {8.f, 16.f, 32.f};

#pragma unroll
    for (int a = 0; a < 9; a++) {
        int rr = a / 3, s = a % 3;
        float hh = 16.f * scl[s] * sqrtf(rat[rr]);
        float wwv = 16.f * scl[s] * sqrtf(1.f / rat[rr]);
        float ab0 = 8.f - 0.5f * hh, ab1 = 8.f - 0.5f * wwv;
        float ab2 = 8.f + 0.5f * hh, ab3 = 8.f + 0.5f * wwv;
        float a0 = sy + ab0, a1c = sx + ab1, a2 = sy + ab2, a3 = sx + ab3;

        float s0 = acc[a * 2 + 0] + sb[a * 2 + 0];
        float s1 = acc[a * 2 + 1] + sb[a * 2 + 1];
        ((float2*)out_sc)[base + a] = make_float2(s0, s1);
        float m = fmaxf(s0, s1);
        float e0 = expf(s0 - m), e1 = expf(s1 - m);
        float fg = e1 / (e0 + e1);

        float dy = acc[18 + a * 4 + 0] + lb[a * 4 + 0];
        float dx = acc[18 + a * 4 + 1] + lb[a * 4 + 1];
        float dh = acc[18 + a * 4 + 2] + lb[a * 4 + 2];
        float dw = acc[18 + a * 4 + 3] + lb[a * 4 + 3];
        ((float4*)out_loc)[base + a] = make_float4(dy, dx, dh, dw);

        float h_ = a2 - a0, w_ = a3 - a1c;
        float cy = a0 + 0.5f * h_, cx = a1c + 0.5f * w_;
        float ncy = dy * h_ + cy, ncx = dx * w_ + cx;
        float nh = expf(dh) * h_, nw = expf(dw) * w_;
        float y1 = ncy - 0.5f * nh, x1 = ncx - 0.5f * nw;
        float y2 = ncy + 0.5f * nh, x2 = ncx + 0.5f * nw;
        y1 = fminf(fmaxf(y1, 0.f), ihf);
        x1 = fminf(fmaxf(x1, 0.f), iwf);
        y2 = fminf(fmaxf(y2, 0.f), ihf);
        x2 = fminf(fmaxf(x2, 0.f), iwf);
        float hs = y2 - y1, wsz = x2 - x1;
        bool valid = (hs >= 16.f) && (wsz >= 16.f);
        ((float4*)boxes)[base + a] = make_float4(y1, x1, y2, x2);
        scf[base + a] = valid ? fg : NEG_INF_F;
    }
}

// ---------------- anchors output ----------------
__global__ void anch_k(float* __restrict__ out_anchor) {
    int i = blockIdx.x * 256 + threadIdx.x;
    if (i >= NANCH) return;
    int p = i / 9, a = i - p * 9;
    int y = p / 64, xq = p - y * 64;
    int r = a / 3, s = a - r * 3;
    const float rat[3] = {0.5f, 1.f, 2.f};
    const float scl[3] = {8.f, 16.f, 32.f};
    float hh = 16.f * scl[s] * sqrtf(rat[r]);
    float wwv = 16.f * scl[s] * sqrtf(1.f / rat[r]);
    float ab0 = 8.f - 0.5f * hh, ab1 = 8.f - 0.5f * wwv;
    float ab2 = 8.f + 0.5f * hh, ab3 = 8.f + 0.5f * wwv;
    float sy = 16.f * (float)y, sx = 16.f * (float)xq;
    ((float4*)out_anchor)[i] = make_float4(sy + ab0, sx + ab1, sy + ab2, sx + ab3);
}

// ---------------- radix select: exact rank-6000 value per batch ----------------
__global__ __launch_bounds__(1024) void radix_k(const float* __restrict__ scf, u32* __restrict__ uT) {
    const int b = blockIdx.x;
    const int tid = threadIdx.x;
    const float* s = scf + (size_t)b * NANCH;
    __shared__ u32 hist[256];
    __shared__ u32 sel_prefix;
    __shared__ int sel_rank;
    if (tid == 0) { sel_prefix = 0u; sel_rank = NPRE; }
    __syncthreads();
    for (int p = 3; p >= 0; --p) {
        for (int i = tid; i < 256; i += 1024) hist[i] = 0u;
        __syncthreads();
        u32 prefix = sel_prefix;
        u32 highmask = (p == 3) ? 0u : (0xFFFFFFFFu << ((p + 1) * 8));
        for (int i = tid; i < NANCH; i += 1024) {
            u32 u = fsort(s[i]);
            if ((u & highmask) == prefix)
                atomicAdd(&hist[(u >> (p * 8)) & 255], 1u);
        }
        __syncthreads();
        if (tid == 0) {
            int r = sel_rank;
            u32 accum = 0;
            int bsel = 0;
            for (int bb = 255; bb >= 0; --bb) {
                accum += hist[bb];
                if ((int)accum >= r) {
                    bsel = bb;
                    sel_rank = r - (int)(accum - hist[bb]);
                    break;
                }
            }
            sel_prefix = prefix | ((u32)bsel << (p * 8));
        }
        __syncthreads();
    }
    if (tid == 0) uT[b] = sel_prefix;
}

// ---------------- compact: gather valid entries with score >= threshold ----------------
__global__ void compact_k(const float* __restrict__ scf, const u32* __restrict__ uT,
                          u32* __restrict__ cnt, u32* __restrict__ cidx) {
    int b = blockIdx.y;
    int i = blockIdx.x * 256 + threadIdx.x;
    float s = scf[(size_t)b * NANCH + i];
    u32 u = fsort(s);
    if (u >= uT[b] && s > -5e29f) {
        u32 p = atomicAdd(&cnt[b], 1u);
        if (p < CAP) cidx[(size_t)b * CAP + p] = (u32)i;
    }
}

// ---------------- sort: per-batch bitonic desc over keys, truncate to 6000, gather boxes
__global__ __launch_bounds__(1024) void sort_k(const float* __restrict__ scf,
                                               const float* __restrict__ boxes,
                                               u32* __restrict__ cnt,
                                               const u32* __restrict__ cidx,
                                               float4* __restrict__ sbox) {
    __shared__ u64 sk[8192];   // 64 KB
    const int b = blockIdx.x;
    const int tid = threadIdx.x;
    int count = (int)cnt[b];
    if (count > CAP) count = CAP;

    for (int i = tid; i < 8192; i += 1024) {
        u64 key = 0ull;
        if (i < count) {
            u32 idx = cidx[(size_t)b * CAP + i];
            u32 u = fsort(scf[(size_t)b * NANCH + idx]);
            key = ((u64)u << 32) | (u64)(0xFFFFFFFFu - idx);
        }
        sk[i] = key;
    }

    for (int k = 2; k <= 8192; k <<= 1) {
        for (int j = k >> 1; j > 0; j >>= 1) {
            __syncthreads();
            for (int i = tid; i < 8192; i += 1024) {
                int p = i ^ j;
                if (p > i) {
                    bool up = (i & k) == 0;     // descending overall
                    u64 a = sk[i], c = sk[p];
                    bool sw = up ? (a < c) : (a > c);
                    if (sw) { sk[i] = c; sk[p] = a; }
                }
            }
        }
    }
    __syncthreads();

    int S = count < NKEEP ? count : NKEEP;
    if (tid == 0) cnt[4 + b] = (u32)S;
    const float4* Bx = (const float4*)boxes;
    for (int i = tid; i < S; i += 1024) {
        u32 idx = 0xFFFFFFFFu - (u32)(sk[i] & 0xFFFFFFFFull);
        sbox[(size_t)b * CAP + i] = Bx[(size_t)b * NANCH + idx];
    }
}

// ---------------- mask build: bit (j,k) = IoU(sorted_j, sorted_k) > 0.7 ----------------
// grid (94 row-tiles, 4 batch), block 256 (4 waves x 64 cols)
__global__ __launch_bounds__(256) void mask_k(const float4* __restrict__ sbox,
                                              const u32* __restrict__ cnt,
                                              u32* __restrict__ mask) {
    __shared__ float4 rb[64];
    __shared__ float ra[64];
    const int tile = blockIdx.x;
    const int b = blockIdx.y;
    const int tid = threadIdx.x;
    const int lane = tid & 63;
    const int wv = tid >> 6;
    const int r0 = tile * 64;

    if (tid < 64) {
        float4 v = sbox[(size_t)b * CAP + (r0 + tid)];
        rb[tid] = v;
        ra[tid] = (v.z - v.x) * (v.w - v.y);
    }
    __syncthreads();

    for (int chunk = (tile >> 2); chunk < 24; ++chunk) {
        int c = chunk * 256 + tid;
        float4 cb = sbox[(size_t)b * CAP + c];
        float a2 = (cb.z - cb.x) * (cb.w - cb.y);
        u64 mine = 0ull;
#pragma unroll 4
        for (int r = 0; r < 64; ++r) {
            float4 rr = rb[r];
            float ty = fmaxf(rr.x, cb.x);
            float tx = fmaxf(rr.y, cb.y);
            float by = fminf(rr.z, cb.z);
            float bx = fminf(rr.w, cb.w);
            float ih = fmaxf(by - ty, 0.f);
            float iw = fmaxf(bx - tx, 0.f);
            float inter = ih * iw;
            float iou = inter / fmaxf(ra[r] + a2 - inter, 1e-6f);
            u64 bal = __ballot(iou > 0.7f);
            if (lane == r) mine = bal;
        }
        int row = r0 + lane;
        u64* dst = (u64*)(mask + ((size_t)b * MROWS + row) * MW);
        dst[chunk * 4 + wv] = mine;
    }
}

// ---------------- scan: single-wave greedy over alive bitset ----------------
__global__ __launch_bounds__(64) void scan_k(const u32* __restrict__ mask,
                                             const float4* __restrict__ sbox,
                                             const u32* __restrict__ cnt,
                                             float4* __restrict__ out_rois) {
    const int b = blockIdx.x;
    const int lane = threadIdx.x;
    const int S = (int)cnt[4 + b];

    __shared__ int keep[NPOST];

    // alive words: lane owns words {lane, 64+lane, 128+lane}; word w covers cands [32w,32w+32)
    u32 a0, a1, a2v;
    {
        int w;
        w = lane;       a0  = (w * 32 + 32 <= S) ? 0xFFFFFFFFu : ((w * 32 < S) ? ((1u << (S - w * 32)) - 1u) : 0u);
        w = 64 + lane;  a1  = (w * 32 + 32 <= S) ? 0xFFFFFFFFu : ((w * 32 < S) ? ((1u << (S - w * 32)) - 1u) : 0u);
        w = 128 + lane; a2v = (w * 32 + 32 <= S) ? 0xFFFFFFFFu : ((w * 32 < S) ? ((1u << (S - w * 32)) - 1u) : 0u);
    }

    const u32* mbase = mask + (size_t)b * MROWS * MW;
    int it = 0;
    while (it < NPOST) {
        int j;
        u64 b0 = __ballot(a0 != 0u);
        if (b0) {
            int L = __builtin_ctzll(b0);
            int cv = (lane << 5) + ctz32(a0);
            j = __shfl(cv, L);
        } else {
            u64 b1 = __ballot(a1 != 0u);
            if (b1) {
                int L = __builtin_ctzll(b1);
                int cv = ((64 + lane) << 5) + ctz32(a1);
                j = __shfl(cv, L);
            } else {
                u64 b2 = __ballot(a2v != 0u);
                if (!b2) break;
                int L = __builtin_ctzll(b2);
                int cv = ((128 + lane) << 5) + ctz32(a2v);
                j = __shfl(cv, L);
            }
        }
        if (lane == 0) keep[it] = j;
        ++it;

        // explicit self-clear (robustness) then AND out suppression row
        int wj = j >> 5;
        u32 bit = 1u << (j & 31);
        if (wj == lane) a0 &= ~bit;
        else if (wj == 64 + lane) a1 &= ~bit;
        else if (wj == 128 + lane) a2v &= ~bit;

        const u32* row = mbase + (size_t)j * MW;
        u32 m0 = row[lane];
        u32 m1 = row[64 + lane];
        u32 m2 = row[128 + lane];
        a0 &= ~m0; a1 &= ~m1; a2v &= ~m2;
    }

    __syncthreads();

    int total = it;
    for (int i = lane; i < NPOST; i += 64) {
        float4 v = make_float4(0.f, 0.f, 0.f, 0.f);
        if (i < total) v = sbox[(size_t)b * CAP + keep[i]];
        out_rois[(size_t)b * NPOST + i] = v;
    }
}

// ---------------- launch ----------------
extern "C" void kernel_launch(void* const* d_in, const int* in_sizes, int n_in,
                              void* d_out, int out_size, void* d_ws, size_t ws_size,
                              hipStream_t stream) {
    const float* x  = (const float*)d_in[0];
    const float* w1 = (const float*)d_in[1];
    const float* b1 = (const float*)d_in[2];
    const float* sw = (const float*)d_in[3];
    const float* sb = (const float*)d_in[4];
    const float* lw = (const float*)d_in[5];
    const float* lb = (const float*)d_in[6];
    const int* ih   = (const int*)d_in[7];
    const int* iw   = (const int*)d_in[8];
    float* out = (float*)d_out;

    char* ws = (char*)d_ws;
    // Region A [0, 31064064): Wp + feat during conv/head; reused as mask afterwards.
    ushort_t* Wp  = (ushort_t*)(ws);                 // 14155776 B
    float* feat   = (float*)(ws + 14286848);         // 16777216 B -> 31064064
    u32* mask     = (u32*)(ws);                      // 4*6016*768 = 18481152 B (after head)
    // Region B (persistent):
    float* wt1    = (float*)(ws + 31064064);         // 131072
    float* boxes  = (float*)(ws + 31195136);         // 2359296
    float* scf    = (float*)(ws + 33554432);         // 589824
    u32* uT       = (u32*)(ws + 34144256);
    u32* cnt      = (u32*)(ws + 34144512);
    u32* cidx     = (u32*)(ws + 34144768);           // 98304
    float4* sbox  = (float4*)(ws + 34243072);        // 393216 -> end 34636288

    float* out_loc = out;                  // 589824 floats
    float* out_sc  = out + 589824;         // 294912 floats
    float4* out_roi = (float4*)(out + 884736);  // 4800 floats
    float* out_anc = out + 889536;         // 147456 floats

    hipLaunchKernelGGL(init_k, dim3(1), dim3(64), 0, stream, cnt);
    hipLaunchKernelGGL(wpack_k, dim3(128), dim3(256), 0, stream, w1, Wp);
    hipLaunchKernelGGL(tw1_k, dim3(128), dim3(256), 0, stream, sw, lw, wt1);
    hipLaunchKernelGGL(anch_k, dim3(144), dim3(256), 0, stream, out_anc);

    for (int pass = 0; pass < 2; ++pass) {
        hipLaunchKernelGGL(conv_mfma_k, dim3(256), dim3(256), 0, stream, x, Wp, b1, feat, pass);
        hipLaunchKernelGGL(head_k, dim3(64, 2), dim3(64), 0, stream, feat, wt1, sb, lb, ih, iw,
                           out_loc, out_sc, boxes, scf, pass);
    }

    hipLaunchKernelGGL(radix_k, dim3(4), dim3(1024), 0, stream, scf, uT);
    hipLaunchKernelGGL(compact_k, dim3(144, 4), dim3(256), 0, stream, scf, uT, cnt, cidx);
    hipLaunchKernelGGL(sort_k, dim3(4), dim3(1024), 0, stream, scf, boxes, cnt, cidx, sbox);
    hipLaunchKernelGGL(mask_k, dim3(94, 4), dim3(256), 0, stream, sbox, cnt, mask);
    hipLaunchKernelGGL(scan_k, dim3(4), dim3(64), 0, stream, mask, sbox, cnt, out_roi);
}

// Round 5
// 1171.277 us; speedup vs baseline: 1.8285x; 1.2827x over previous
//
#include <hip/hip_runtime.h>
#include <stdint.h>

typedef unsigned int u32;
typedef unsigned long long u64;
typedef unsigned short ushort_t;

#define NANCH 36864        // 4096*9
#define NPRE 6000
#define NPOST 300
#define CAP 6144
#define NKEEP 6000         // exact top-k truncation
#define MROWS 6016         // mask rows padded (94*64)
#define MW 192             // u32 words per mask row (6144 bits)
#define NEG_INF_F (-1e30f)

typedef __attribute__((ext_vector_type(8))) __bf16 bf8_t;
typedef __attribute__((ext_vector_type(8))) unsigned short us8_t;
typedef __attribute__((ext_vector_type(16))) float f32x16;

union pun8 { us8_t u; bf8_t b; };

// monotonic float->uint mapping (ascending)
__device__ __forceinline__ u32 fsort(float f) {
    u32 u = __float_as_uint(f);
    return (u & 0x80000000u) ? ~u : (u | 0x80000000u);
}

// RNE float -> bf16 bits, and exact bf16 bits -> float
__device__ __forceinline__ unsigned short f2bf(float f) {
    u32 u = __float_as_uint(f);
    u32 r = (u + 0x7FFFu + ((u >> 16) & 1u)) >> 16;
    return (unsigned short)r;
}
__device__ __forceinline__ float bf2f(unsigned short s) {
    return __uint_as_float(((u32)s) << 16);
}

// safe ctz: identity for nonzero input; defined (0) for zero (result unused then)
__device__ __forceinline__ int ctz32(u32 x) {
    return __builtin_ctz(x ? x : 1u);
}

// ---------------- init: zero the compact counters ----------------
__global__ void init_k(u32* cnt) {
    if (threadIdx.x < 8) cnt[threadIdx.x] = 0u;
}

// ---------------- weight prepack: fp32 OIHW -> bf16x3 split, MFMA-A-fragment order
__global__ void wpack_k(const float* __restrict__ w, ushort_t* __restrict__ Wp) {
    int T = blockIdx.x * 256 + threadIdx.x;   // 0..32767
    if (T >= 32768) return;
    int lane31 = T & 31;
    int cot    = (T >> 5) & 15;
    int khalf  = (T >> 9) & 1;
    int kc     = T >> 10;                      // 0..31
    int co  = cot * 32 + lane31;
    int ci0 = kc * 16 + khalf * 8;
    int lane = lane31 + khalf * 32;
    const float* wr = w + (size_t)co * 4608 + (size_t)ci0 * 9;
    us8_t* P = (us8_t*)Wp;
    const size_t sa_stride = (size_t)9 * 32 * 16 * 64;   // us8 units per split
#pragma unroll
    for (int t = 0; t < 9; ++t) {
        us8_t vh, vm, vl;
#pragma unroll
        for (int j = 0; j < 8; ++j) {
            float v = wr[j * 9 + t];
            unsigned short h = f2bf(v); float r1 = v - bf2f(h);
            unsigned short m = f2bf(r1); float r2 = r1 - bf2f(m);
            vh[j] = h; vm[j] = m; vl[j] = f2bf(r2);
        }
        size_t base = ((((size_t)t) * 32 + kc) * 16 + cot) * 64 + lane;
        P[base] = vh;
        P[base + sa_stride] = vm;
        P[base + 2 * sa_stride] = vl;
    }
}

// ---------------- pack 1x1 weights to [ci][64] ----------------
__global__ void tw1_k(const float* __restrict__ sw, const float* __restrict__ lw,
                      float* __restrict__ wt1) {
    int i = blockIdx.x * 256 + threadIdx.x;
    if (i >= 512 * 64) return;
    int ci = i >> 6;
    int ch = i & 63;
    float v = 0.f;
    if (ch < 18) v = sw[ch * 512 + ci];
    else if (ch < 54) v = lw[(ch - 18) * 512 + ci];
    wt1[i] = v;
}

// ---------------- conv1 via bf16x6 MFMA ----------------
// Grid = 128 * nimg blocks (256 thr). Block tile: 128 co (coq) x 128 px (2 rows).
// Decode: xcd=bid&7 pins a co-quarter's weights to an XCD pair (L2 locality);
// g = (xcd&1)*(grid/8) + (bid>>3) enumerates (img, h-pair).
__global__ __launch_bounds__(256, 2) void conv_mfma_k(const float* __restrict__ x,
                                                      const ushort_t* __restrict__ Wp,
                                                      const float* __restrict__ bias,
                                                      float* __restrict__ feat,
                                                      int img_base) {
    __shared__ __align__(16) unsigned short xs[3 * 6336];   // 38016 B

    const int bid = blockIdx.x;
    const int xcd = bid & 7;
    const int rest = bid >> 3;
    const int rest_max = gridDim.x >> 3;
    const int coq = xcd >> 1;
    const int g = (xcd & 1) * rest_max + rest;
    const int fimg = g >> 5;                   // feat image index
    const int hp = g & 31;
    const int n = img_base + fimg;             // source image
    const int h0 = hp * 2;

    const int tid = threadIdx.x;
    const int lane = tid & 63;
    const int wv = tid >> 6;
    const int r = wv >> 1;
    const int wb = (wv & 1) * 32;
    const int col31 = lane & 31;
    const int halfk = lane >> 5;

    f32x16 acc[4];
#pragma unroll
    for (int q = 0; q < 4; ++q)
#pragma unroll
        for (int i = 0; i < 16; ++i) acc[q][i] = 0.f;

    const us8_t* Pw = (const us8_t*)Wp;
    const size_t sa_stride = (size_t)9 * 32 * 16 * 64;
    static const int sal[6] = {0, 0, 1, 0, 1, 2};
    static const int sbl[6] = {0, 1, 0, 2, 1, 0};

    for (int kc = 0; kc < 32; ++kc) {
        for (int e = tid; e < 528; e += 256) {
            int half = e & 1;
            int rc = e >> 1;
            int rr = rc / 66;
            int cc = rc - rr * 66;
            int gr = h0 + rr - 1;
            int gc = cc - 1;
            bool inb = ((unsigned)gr < 64u) && ((unsigned)gc < 64u);
            int ci0 = kc * 16 + half * 8;
            const float* xp = x + ((((size_t)n * 512 + ci0) * 64 + gr) * 64 + gc);
            us8_t vh, vm, vl;
#pragma unroll
            for (int j = 0; j < 8; ++j) {
                float v = inb ? xp[(size_t)j * 4096] : 0.f;
                unsigned short h = f2bf(v); float r1 = v - bf2f(h);
                unsigned short m = f2bf(r1); float r2 = r1 - bf2f(m);
                vh[j] = h; vm[j] = m; vl[j] = f2bf(r2);
            }
            int off = (rr * 66 + cc) * 24 + half * 8;
            *(us8_t*)&xs[off] = vh;
            *(us8_t*)&xs[6336 + off] = vm;
            *(us8_t*)&xs[12672 + off] = vl;
        }
        __syncthreads();

#pragma unroll
        for (int t = 0; t < 9; ++t) {
            const int kh = t / 3, kw = t - kh * 3;
            pun8 Bf[3];
            int boff = ((r + kh) * 66 + (wb + col31 + kw)) * 24 + halfk * 8;
#pragma unroll
            for (int sb = 0; sb < 3; ++sb)
                Bf[sb].u = *(const us8_t*)&xs[sb * 6336 + boff];
            pun8 Af[3][4];
            size_t abase = (((size_t)t * 32 + kc) * 16 + coq * 4) * 64 + lane;
#pragma unroll
            for (int sa = 0; sa < 3; ++sa)
#pragma unroll
                for (int q = 0; q < 4; ++q)
                    Af[sa][q].u = Pw[sa * sa_stride + abase + (size_t)q * 64];
#pragma unroll
            for (int pp = 0; pp < 6; ++pp) {
                const int sa = sal[pp], sb = sbl[pp];
#pragma unroll
                for (int q = 0; q < 4; ++q)
                    acc[q] = __builtin_amdgcn_mfma_f32_32x32x16_bf16(
                        Af[sa][q].b, Bf[sb].b, acc[q], 0, 0, 0);
            }
        }
        __syncthreads();
    }

#pragma unroll
    for (int q = 0; q < 4; ++q) {
#pragma unroll
        for (int i = 0; i < 16; ++i) {
            int m = (i & 3) + 8 * (i >> 2) + 4 * halfk;
            int co = coq * 128 + q * 32 + m;
            float v = acc[q][i] + bias[co];
            v = v > 0.f ? v : 0.f;
            feat[(((size_t)fimg * 512 + co) * 64 + (h0 + r)) * 64 + (wb + col31)] = v;
        }
    }
}

// ---------------- head: 1x1 convs + softmax-fg + loc2bbox + clip + valid ----------------
// grid (64 rows, nimg), block 64 (lane = w)
__global__ __launch_bounds__(64) void head_k(const float* __restrict__ feat,
                                             const float* __restrict__ wt1,
                                             const float* __restrict__ sb,
                                             const float* __restrict__ lb,
                                             const int* __restrict__ img_h,
                                             const int* __restrict__ img_w,
                                             float* __restrict__ out_loc,
                                             float* __restrict__ out_sc,
                                             float* __restrict__ boxes,
                                             float* __restrict__ scf,
                                             int img_base) {
    const int lane = threadIdx.x;
    const int row = blockIdx.x;
    const int fimg = blockIdx.y;
    const int n = img_base + fimg;

    float acc[56];
#pragma unroll
    for (int i = 0; i < 56; i++) acc[i] = 0.f;

    for (int ci = 0; ci < 512; ++ci) {
        float f = feat[(((size_t)fimg * 512 + ci) * 64 + row) * 64 + lane];
        const float4* wp = (const float4*)(wt1 + ci * 64);
#pragma unroll
        for (int q = 0; q < 14; q++) {
            float4 w4 = wp[q];
            acc[q * 4 + 0] = fmaf(f, w4.x, acc[q * 4 + 0]);
            acc[q * 4 + 1] = fmaf(f, w4.y, acc[q * 4 + 1]);
            acc[q * 4 + 2] = fmaf(f, w4.z, acc[q * 4 + 2]);
            acc[q * 4 + 3] = fmaf(f, w4.w, acc[q * 4 + 3]);
        }
    }

    float ihf = (float)img_h[0];
    float iwf = (float)img_w[0];
    int p = row * 64 + lane;
    size_t base = (size_t)n * NANCH + (size_t)p * 9;
    float sy = 16.f * (float)row;
    float sx = 16.f * (float)lane;
    const float rat[3] = {0.5f, 1.f, 2.f};
    const float scl[3] = {8.f, 16.f, 32.f};

#pragma unroll
    for (int a = 0; a < 9; a++) {
        int rr = a / 3, s = a % 3;
        float hh = 16.f * scl[s] * sqrtf(rat[rr]);
        float wwv = 16.f * scl[s] * sqrtf(1.f / rat[rr]);
        float ab0 = 8.f - 0.5f * hh, ab1 = 8.f - 0.5f * wwv;
        float ab2 = 8.f + 0.5f * hh, ab3 = 8.f + 0.5f * wwv;
        float a0 = sy + ab0, a1c = sx + ab1, a2 = sy + ab2, a3 = sx + ab3;

        float s0 = acc[a * 2 + 0] + sb[a * 2 + 0];
        float s1 = acc[a * 2 + 1] + sb[a * 2 + 1];
        ((float2*)out_sc)[base + a] = make_float2(s0, s1);
        float m = fmaxf(s0, s1);
        float e0 = expf(s0 - m), e1 = expf(s1 - m);
        float fg = e1 / (e0 + e1);

        float dy = acc[18 + a * 4 + 0] + lb[a * 4 + 0];
        float dx = acc[18 + a * 4 + 1] + lb[a * 4 + 1];
        float dh = acc[18 + a * 4 + 2] + lb[a * 4 + 2];
        float dw = acc[18 + a * 4 + 3] + lb[a * 4 + 3];
        ((float4*)out_loc)[base + a] = make_float4(dy, dx, dh, dw);

        float h_ = a2 - a0, w_ = a3 - a1c;
        float cy = a0 + 0.5f * h_, cx = a1c + 0.5f * w_;
        float ncy = dy * h_ + cy, ncx = dx * w_ + cx;
        float nh = expf(dh) * h_, nw = expf(dw) * w_;
        float y1 = ncy - 0.5f * nh, x1 = ncx - 0.5f * nw;
        float y2 = ncy + 0.5f * nh, x2 = ncx + 0.5f * nw;
        y1 = fminf(fmaxf(y1, 0.f), ihf);
        x1 = fminf(fmaxf(x1, 0.f), iwf);
        y2 = fminf(fmaxf(y2, 0.f), ihf);
        x2 = fminf(fmaxf(x2, 0.f), iwf);
        float hs = y2 - y1, wsz = x2 - x1;
        bool valid = (hs >= 16.f) && (wsz >= 16.f);
        ((float4*)boxes)[base + a] = make_float4(y1, x1, y2, x2);
        scf[base + a] = valid ? fg : NEG_INF_F;
    }
}

// ---------------- anchors output ----------------
__global__ void anch_k(float* __restrict__ out_anchor) {
    int i = blockIdx.x * 256 + threadIdx.x;
    if (i >= NANCH) return;
    int p = i / 9, a = i - p * 9;
    int y = p / 64, xq = p - y * 64;
    int r = a / 3, s = a - r * 3;
    const float rat[3] = {0.5f, 1.f, 2.f};
    const float scl[3] = {8.f, 16.f, 32.f};
    float hh = 16.f * scl[s] * sqrtf(rat[r]);
    float wwv = 16.f * scl[s] * sqrtf(1.f / rat[r]);
    float ab0 = 8.f - 0.5f * hh, ab1 = 8.f - 0.5f * wwv;
    float ab2 = 8.f + 0.5f * hh, ab3 = 8.f + 0.5f * wwv;
    float sy = 16.f * (float)y, sx = 16.f * (float)xq;
    ((float4*)out_anchor)[i] = make_float4(sy + ab0, sx + ab1, sy + ab2, sx + ab3);
}

// ---------------- radix select: exact rank-6000 value per batch ----------------
__global__ __launch_bounds__(1024) void radix_k(const float* __restrict__ scf, u32* __restrict__ uT) {
    const int b = blockIdx.x;
    const int tid = threadIdx.x;
    const float* s = scf + (size_t)b * NANCH;
    __shared__ u32 hist[256];
    __shared__ u32 sel_prefix;
    __shared__ int sel_rank;
    if (tid == 0) { sel_prefix = 0u; sel_rank = NPRE; }
    __syncthreads();
    for (int p = 3; p >= 0; --p) {
        for (int i = tid; i < 256; i += 1024) hist[i] = 0u;
        __syncthreads();
        u32 prefix = sel_prefix;
        u32 highmask = (p == 3) ? 0u : (0xFFFFFFFFu << ((p + 1) * 8));
        for (int i = tid; i < NANCH; i += 1024) {
            u32 u = fsort(s[i]);
            if ((u & highmask) == prefix)
                atomicAdd(&hist[(u >> (p * 8)) & 255], 1u);
        }
        __syncthreads();
        if (tid == 0) {
            int r = sel_rank;
            u32 accum = 0;
            int bsel = 0;
            for (int bb = 255; bb >= 0; --bb) {
                accum += hist[bb];
                if ((int)accum >= r) {
                    bsel = bb;
                    sel_rank = r - (int)(accum - hist[bb]);
                    break;
                }
            }
            sel_prefix = prefix | ((u32)bsel << (p * 8));
        }
        __syncthreads();
    }
    if (tid == 0) uT[b] = sel_prefix;
}

// ---------------- compact: gather valid entries with score >= threshold ----------------
__global__ void compact_k(const float* __restrict__ scf, const u32* __restrict__ uT,
                          u32* __restrict__ cnt, u32* __restrict__ cidx) {
    int b = blockIdx.y;
    int i = blockIdx.x * 256 + threadIdx.x;
    float s = scf[(size_t)b * NANCH + i];
    u32 u = fsort(s);
    if (u >= uT[b] && s > -5e29f) {
        u32 p = atomicAdd(&cnt[b], 1u);
        if (p < CAP) cidx[(size_t)b * CAP + p] = (u32)i;
    }
}

// ---------------- sort: per-batch bitonic desc over keys, truncate to 6000, gather boxes
__global__ __launch_bounds__(1024) void sort_k(const float* __restrict__ scf,
                                               const float* __restrict__ boxes,
                                               u32* __restrict__ cnt,
                                               const u32* __restrict__ cidx,
                                               float4* __restrict__ sbox) {
    __shared__ u64 sk[8192];   // 64 KB
    const int b = blockIdx.x;
    const int tid = threadIdx.x;
    int count = (int)cnt[b];
    if (count > CAP) count = CAP;

    for (int i = tid; i < 8192; i += 1024) {
        u64 key = 0ull;
        if (i < count) {
            u32 idx = cidx[(size_t)b * CAP + i];
            u32 u = fsort(scf[(size_t)b * NANCH + idx]);
            key = ((u64)u << 32) | (u64)(0xFFFFFFFFu - idx);
        }
        sk[i] = key;
    }

    for (int k = 2; k <= 8192; k <<= 1) {
        for (int j = k >> 1; j > 0; j >>= 1) {
            __syncthreads();
            for (int i = tid; i < 8192; i += 1024) {
                int p = i ^ j;
                if (p > i) {
                    bool up = (i & k) == 0;     // descending overall
                    u64 a = sk[i], c = sk[p];
                    bool sw = up ? (a < c) : (a > c);
                    if (sw) { sk[i] = c; sk[p] = a; }
                }
            }
        }
    }
    __syncthreads();

    int S = count < NKEEP ? count : NKEEP;
    if (tid == 0) cnt[4 + b] = (u32)S;
    const float4* Bx = (const float4*)boxes;
    for (int i = tid; i < S; i += 1024) {
        u32 idx = 0xFFFFFFFFu - (u32)(sk[i] & 0xFFFFFFFFull);
        sbox[(size_t)b * CAP + i] = Bx[(size_t)b * NANCH + idx];
    }
}

// ---------------- mask build: bit (j,k) = IoU(sorted_j, sorted_k) > 0.7 ----------------
// grid (94 row-tiles, 4 batch), block 256 (4 waves x 64 cols)
__global__ __launch_bounds__(256) void mask_k(const float4* __restrict__ sbox,
                                              const u32* __restrict__ cnt,
                                              u32* __restrict__ mask) {
    __shared__ float4 rb[64];
    __shared__ float ra[64];
    const int tile = blockIdx.x;
    const int b = blockIdx.y;
    const int tid = threadIdx.x;
    const int lane = tid & 63;
    const int wv = tid >> 6;
    const int r0 = tile * 64;

    if (tid < 64) {
        float4 v = sbox[(size_t)b * CAP + (r0 + tid)];
        rb[tid] = v;
        ra[tid] = (v.z - v.x) * (v.w - v.y);
    }
    __syncthreads();

    for (int chunk = (tile >> 2); chunk < 24; ++chunk) {
        int c = chunk * 256 + tid;
        float4 cb = sbox[(size_t)b * CAP + c];
        float a2 = (cb.z - cb.x) * (cb.w - cb.y);
        u64 mine = 0ull;
#pragma unroll 4
        for (int r = 0; r < 64; ++r) {
            float4 rr = rb[r];
            float ty = fmaxf(rr.x, cb.x);
            float tx = fmaxf(rr.y, cb.y);
            float by = fminf(rr.z, cb.z);
            float bx = fminf(rr.w, cb.w);
            float ih = fmaxf(by - ty, 0.f);
            float iw = fmaxf(bx - tx, 0.f);
            float inter = ih * iw;
            float iou = inter / fmaxf(ra[r] + a2 - inter, 1e-6f);
            u64 bal = __ballot(iou > 0.7f);
            if (lane == r) mine = bal;
        }
        int row = r0 + lane;
        u64* dst = (u64*)(mask + ((size_t)b * MROWS + row) * MW);
        dst[chunk * 4 + wv] = mine;
    }
}

// ---------------- scan: single-wave greedy over alive bitset ----------------
__global__ __launch_bounds__(64) void scan_k(const u32* __restrict__ mask,
                                             const float4* __restrict__ sbox,
                                             const u32* __restrict__ cnt,
                                             float4* __restrict__ out_rois) {
    const int b = blockIdx.x;
    const int lane = threadIdx.x;
    const int S = (int)cnt[4 + b];

    __shared__ int keep[NPOST];

    u32 a0, a1, a2v;
    {
        int w;
        w = lane;       a0  = (w * 32 + 32 <= S) ? 0xFFFFFFFFu : ((w * 32 < S) ? ((1u << (S - w * 32)) - 1u) : 0u);
        w = 64 + lane;  a1  = (w * 32 + 32 <= S) ? 0xFFFFFFFFu : ((w * 32 < S) ? ((1u << (S - w * 32)) - 1u) : 0u);
        w = 128 + lane; a2v = (w * 32 + 32 <= S) ? 0xFFFFFFFFu : ((w * 32 < S) ? ((1u << (S - w * 32)) - 1u) : 0u);
    }

    const u32* mbase = mask + (size_t)b * MROWS * MW;
    int it = 0;
    while (it < NPOST) {
        int j;
        u64 b0 = __ballot(a0 != 0u);
        if (b0) {
            int L = __builtin_ctzll(b0);
            int cv = (lane << 5) + ctz32(a0);
            j = __shfl(cv, L);
        } else {
            u64 b1 = __ballot(a1 != 0u);
            if (b1) {
                int L = __builtin_ctzll(b1);
                int cv = ((64 + lane) << 5) + ctz32(a1);
                j = __shfl(cv, L);
            } else {
                u64 b2 = __ballot(a2v != 0u);
                if (!b2) break;
                int L = __builtin_ctzll(b2);
                int cv = ((128 + lane) << 5) + ctz32(a2v);
                j = __shfl(cv, L);
            }
        }
        if (lane == 0) keep[it] = j;
        ++it;

        int wj = j >> 5;
        u32 bit = 1u << (j & 31);
        if (wj == lane) a0 &= ~bit;
        else if (wj == 64 + lane) a1 &= ~bit;
        else if (wj == 128 + lane) a2v &= ~bit;

        const u32* row = mbase + (size_t)j * MW;
        u32 m0 = row[lane];
        u32 m1 = row[64 + lane];
        u32 m2 = row[128 + lane];
        a0 &= ~m0; a1 &= ~m1; a2v &= ~m2;
    }

    __syncthreads();

    int total = it;
    for (int i = lane; i < NPOST; i += 64) {
        float4 v = make_float4(0.f, 0.f, 0.f, 0.f);
        if (i < total) v = sbox[(size_t)b * CAP + keep[i]];
        out_rois[(size_t)b * NPOST + i] = v;
    }
}

// ---------------- launch ----------------
extern "C" void kernel_launch(void* const* d_in, const int* in_sizes, int n_in,
                              void* d_out, int out_size, void* d_ws, size_t ws_size,
                              hipStream_t stream) {
    const float* x  = (const float*)d_in[0];
    const float* w1 = (const float*)d_in[1];
    const float* b1 = (const float*)d_in[2];
    const float* sw = (const float*)d_in[3];
    const float* sb = (const float*)d_in[4];
    const float* lw = (const float*)d_in[5];
    const float* lb = (const float*)d_in[6];
    const int* ih   = (const int*)d_in[7];
    const int* iw   = (const int*)d_in[8];
    float* out = (float*)d_out;

    char* ws = (char*)d_ws;
    const size_t FEAT_OFF = 14286848;                 // Wp = [0, 14155776)
    const size_t NEED_BIG = 51413504;                 // big layout total bytes
    const bool big = (ws_size >= NEED_BIG);

    // Region A: Wp + feat (2 or 4 images); overlaid by mask after head.
    ushort_t* Wp  = (ushort_t*)(ws);
    float* feat   = (float*)(ws + FEAT_OFF);
    u32* mask     = (u32*)(ws);                       // 4*6016*768 = 18481152 B (dead Wp/feat)
    // Region B (persistent), after feat:
    const size_t RB = big ? (FEAT_OFF + 33554432) : (FEAT_OFF + 16777216);
    float* wt1    = (float*)(ws + RB);                // 131072
    float* boxes  = (float*)(ws + RB + 131072);       // 2359296
    float* scf    = (float*)(ws + RB + 2490368);      // 589824
    u32* uT       = (u32*)(ws + RB + 3080192);
    u32* cnt      = (u32*)(ws + RB + 3080448);
    u32* cidx     = (u32*)(ws + RB + 3080704);        // 98304
    float4* sbox  = (float4*)(ws + RB + 3179008);     // 393216 -> end RB+3572224

    float* out_loc = out;                  // 589824 floats
    float* out_sc  = out + 589824;         // 294912 floats
    float4* out_roi = (float4*)(out + 884736);  // 4800 floats
    float* out_anc = out + 889536;         // 147456 floats

    hipLaunchKernelGGL(init_k, dim3(1), dim3(64), 0, stream, cnt);
    hipLaunchKernelGGL(wpack_k, dim3(128), dim3(256), 0, stream, w1, Wp);
    hipLaunchKernelGGL(tw1_k, dim3(128), dim3(256), 0, stream, sw, lw, wt1);
    hipLaunchKernelGGL(anch_k, dim3(144), dim3(256), 0, stream, out_anc);

    if (big) {
        // single fused dispatch: 512 blocks = 2 blocks/CU -> 2 waves/SIMD
        hipLaunchKernelGGL(conv_mfma_k, dim3(512), dim3(256), 0, stream, x, Wp, b1, feat, 0);
        hipLaunchKernelGGL(head_k, dim3(64, 4), dim3(64), 0, stream, feat, wt1, sb, lb, ih, iw,
                           out_loc, out_sc, boxes, scf, 0);
    } else {
        for (int pass = 0; pass < 2; ++pass) {
            hipLaunchKernelGGL(conv_mfma_k, dim3(256), dim3(256), 0, stream, x, Wp, b1, feat, pass * 2);
            hipLaunchKernelGGL(head_k, dim3(64, 2), dim3(64), 0, stream, feat, wt1, sb, lb, ih, iw,
                               out_loc, out_sc, boxes, scf, pass * 2);
        }
    }

    hipLaunchKernelGGL(radix_k, dim3(4), dim3(1024), 0, stream, scf, uT);
    hipLaunchKernelGGL(compact_k, dim3(144, 4), dim3(256), 0, stream, scf, uT, cnt, cidx);
    hipLaunchKernelGGL(sort_k, dim3(4), dim3(1024), 0, stream, scf, boxes, cnt, cidx, sbox);
    hipLaunchKernelGGL(mask_k, dim3(94, 4), dim3(256), 0, stream, sbox, cnt, mask);
    hipLaunchKernelGGL(scan_k, dim3(4), dim3(64), 0, stream, mask, sbox, cnt, out_roi);
}

// Round 6
// 1113.985 us; speedup vs baseline: 1.9225x; 1.0514x over previous
//
#include <hip/hip_runtime.h>
#include <stdint.h>

typedef unsigned int u32;
typedef unsigned long long u64;
typedef unsigned short ushort_t;

#define NANCH 36864        // 4096*9
#define NPRE 6000
#define NPOST 300
#define CAP 6144
#define NKEEP 6000         // exact top-k truncation
#define MROWS 6016         // mask rows padded (94*64)
#define MW 192             // u32 words per mask row (6144 bits)
#define NEG_INF_F (-1e30f)

typedef __attribute__((ext_vector_type(8))) __bf16 bf8_t;
typedef __attribute__((ext_vector_type(8))) unsigned short us8_t;
typedef __attribute__((ext_vector_type(16))) float f32x16;

union pun8 { us8_t u; bf8_t b; };

// monotonic float->uint mapping (ascending)
__device__ __forceinline__ u32 fsort(float f) {
    u32 u = __float_as_uint(f);
    return (u & 0x80000000u) ? ~u : (u | 0x80000000u);
}

// RNE float -> bf16 bits, and exact bf16 bits -> float
__device__ __forceinline__ unsigned short f2bf(float f) {
    u32 u = __float_as_uint(f);
    u32 r = (u + 0x7FFFu + ((u >> 16) & 1u)) >> 16;
    return (unsigned short)r;
}
__device__ __forceinline__ float bf2f(unsigned short s) {
    return __uint_as_float(((u32)s) << 16);
}

// safe ctz: identity for nonzero input; defined (0) for zero (result unused then)
__device__ __forceinline__ int ctz32(u32 x) {
    return __builtin_ctz(x ? x : 1u);
}

// ---------------- fused setup: wpack (128 blk) | tw1 (128) | anch (144) | init (1)
__global__ void setup_k(const float* __restrict__ w1, const float* __restrict__ sw,
                        const float* __restrict__ lw, ushort_t* __restrict__ Wp,
                        float* __restrict__ wt1, float* __restrict__ out_anchor,
                        u32* __restrict__ cnt) {
    const int bid = blockIdx.x;
    const int tid = threadIdx.x;
    if (bid < 128) {
        // weight prepack: fp32 OIHW -> bf16x3 split, MFMA-A-fragment order
        int T = bid * 256 + tid;
        int lane31 = T & 31;
        int cot    = (T >> 5) & 15;
        int khalf  = (T >> 9) & 1;
        int kc     = T >> 10;
        int co  = cot * 32 + lane31;
        int ci0 = kc * 16 + khalf * 8;
        int lane = lane31 + khalf * 32;
        const float* wr = w1 + (size_t)co * 4608 + (size_t)ci0 * 9;
        us8_t* P = (us8_t*)Wp;
        const size_t sa_stride = (size_t)9 * 32 * 16 * 64;
#pragma unroll
        for (int t = 0; t < 9; ++t) {
            us8_t vh, vm, vl;
#pragma unroll
            for (int j = 0; j < 8; ++j) {
                float v = wr[j * 9 + t];
                unsigned short h = f2bf(v); float r1 = v - bf2f(h);
                unsigned short m = f2bf(r1); float r2 = r1 - bf2f(m);
                vh[j] = h; vm[j] = m; vl[j] = f2bf(r2);
            }
            size_t base = ((((size_t)t) * 32 + kc) * 16 + cot) * 64 + lane;
            P[base] = vh;
            P[base + sa_stride] = vm;
            P[base + 2 * sa_stride] = vl;
        }
    } else if (bid < 256) {
        int i = (bid - 128) * 256 + tid;
        int ci = i >> 6;
        int ch = i & 63;
        float v = 0.f;
        if (ch < 18) v = sw[ch * 512 + ci];
        else if (ch < 54) v = lw[(ch - 18) * 512 + ci];
        wt1[i] = v;
    } else if (bid < 400) {
        int i = (bid - 256) * 256 + tid;
        if (i < NANCH) {
            int p = i / 9, a = i - p * 9;
            int y = p / 64, xq = p - y * 64;
            int r = a / 3, s = a - r * 3;
            const float rat[3] = {0.5f, 1.f, 2.f};
            const float scl[3] = {8.f, 16.f, 32.f};
            float hh = 16.f * scl[s] * sqrtf(rat[r]);
            float wwv = 16.f * scl[s] * sqrtf(1.f / rat[r]);
            float ab0 = 8.f - 0.5f * hh, ab1 = 8.f - 0.5f * wwv;
            float ab2 = 8.f + 0.5f * hh, ab3 = 8.f + 0.5f * wwv;
            float sy = 16.f * (float)y, sx = 16.f * (float)xq;
            ((float4*)out_anchor)[i] = make_float4(sy + ab0, sx + ab1, sy + ab2, sx + ab3);
        }
    } else {
        if (tid < 8) cnt[tid] = 0u;
    }
}

// ---------------- conv1 via bf16x6 MFMA ----------------
// Grid = 128 * nimg blocks (256 thr). Block tile: 128 co (coq) x 128 px (2 rows).
// Wave tile 2x2: coh=(wv>>1)*64 co-half, r=wv&1 row; 2 co-subtiles x 2 px-col-subtiles.
// Per (kc,t): 6 global A-frag loads + 6 LDS B-frag loads -> 24 MFMAs.
__global__ __launch_bounds__(256, 2) void conv_mfma_k(const float* __restrict__ x,
                                                      const ushort_t* __restrict__ Wp,
                                                      const float* __restrict__ bias,
                                                      float* __restrict__ feat,
                                                      int img_base) {
    __shared__ __align__(16) unsigned short xs[3 * 6336];   // 38016 B

    const int bid = blockIdx.x;
    const int xcd = bid & 7;
    const int rest = bid >> 3;
    const int rest_max = gridDim.x >> 3;
    const int coq = xcd >> 1;
    const int g = (xcd & 1) * rest_max + rest;
    const int fimg = g >> 5;
    const int hp = g & 31;
    const int n = img_base + fimg;
    const int h0 = hp * 2;

    const int tid = threadIdx.x;
    const int lane = tid & 63;
    const int wv = tid >> 6;
    const int r = wv & 1;                       // row within pair
    const int coh = (wv >> 1);                  // co half (0/1 -> 64 co)
    const int col31 = lane & 31;
    const int halfk = lane >> 5;

    f32x16 acc[4];
#pragma unroll
    for (int q = 0; q < 4; ++q)
#pragma unroll
        for (int i = 0; i < 16; ++i) acc[q][i] = 0.f;

    const us8_t* Pw = (const us8_t*)Wp;
    const size_t sa_stride = (size_t)9 * 32 * 16 * 64;
    static const int sal[6] = {0, 0, 1, 0, 1, 2};
    static const int sbl[6] = {0, 1, 0, 2, 1, 0};

    for (int kc = 0; kc < 32; ++kc) {
        for (int e = tid; e < 528; e += 256) {
            int half = e & 1;
            int rc = e >> 1;
            int rr = rc / 66;
            int cc = rc - rr * 66;
            int gr = h0 + rr - 1;
            int gc = cc - 1;
            bool inb = ((unsigned)gr < 64u) && ((unsigned)gc < 64u);
            int ci0 = kc * 16 + half * 8;
            const float* xp = x + ((((size_t)n * 512 + ci0) * 64 + gr) * 64 + gc);
            us8_t vh, vm, vl;
#pragma unroll
            for (int j = 0; j < 8; ++j) {
                float v = inb ? xp[(size_t)j * 4096] : 0.f;
                unsigned short h = f2bf(v); float r1 = v - bf2f(h);
                unsigned short m = f2bf(r1); float r2 = r1 - bf2f(m);
                vh[j] = h; vm[j] = m; vl[j] = f2bf(r2);
            }
            int off = (rr * 66 + cc) * 24 + half * 8;
            *(us8_t*)&xs[off] = vh;
            *(us8_t*)&xs[6336 + off] = vm;
            *(us8_t*)&xs[12672 + off] = vl;
        }
        __syncthreads();

#pragma unroll
        for (int t = 0; t < 9; ++t) {
            const int kh = t / 3, kw = t - kh * 3;
            pun8 Bf[3][2];
            int boff0 = ((r + kh) * 66 + (col31 + kw)) * 24 + halfk * 8;
#pragma unroll
            for (int sb = 0; sb < 3; ++sb)
#pragma unroll
                for (int ps = 0; ps < 2; ++ps)
                    Bf[sb][ps].u = *(const us8_t*)&xs[sb * 6336 + boff0 + ps * (32 * 24)];
            pun8 Af[3][2];
            size_t abase = (((size_t)t * 32 + kc) * 16 + coq * 4 + coh * 2) * 64 + lane;
#pragma unroll
            for (int sa = 0; sa < 3; ++sa)
#pragma unroll
                for (int cs = 0; cs < 2; ++cs)
                    Af[sa][cs].u = Pw[sa * sa_stride + abase + (size_t)cs * 64];
#pragma unroll
            for (int pp = 0; pp < 6; ++pp) {
                const int sa = sal[pp], sb = sbl[pp];
#pragma unroll
                for (int cs = 0; cs < 2; ++cs)
#pragma unroll
                    for (int ps = 0; ps < 2; ++ps)
                        acc[cs * 2 + ps] = __builtin_amdgcn_mfma_f32_32x32x16_bf16(
                            Af[sa][cs].b, Bf[sb][ps].b, acc[cs * 2 + ps], 0, 0, 0);
            }
        }
        __syncthreads();
    }

#pragma unroll
    for (int cs = 0; cs < 2; ++cs)
#pragma unroll
        for (int ps = 0; ps < 2; ++ps)
#pragma unroll
            for (int i = 0; i < 16; ++i) {
                int m = (i & 3) + 8 * (i >> 2) + 4 * halfk;
                int co = coq * 128 + coh * 64 + cs * 32 + m;
                float v = acc[cs * 2 + ps][i] + bias[co];
                v = v > 0.f ? v : 0.f;
                feat[(((size_t)fimg * 512 + co) * 64 + (h0 + r)) * 64 + (ps * 32 + col31)] = v;
            }
}

// ---------------- head: 1x1 convs + softmax-fg + loc2bbox + clip + valid ----------------
__global__ __launch_bounds__(64) void head_k(const float* __restrict__ feat,
                                             const float* __restrict__ wt1,
                                             const float* __restrict__ sb,
                                             const float* __restrict__ lb,
                                             const int* __restrict__ img_h,
                                             const int* __restrict__ img_w,
                                             float* __restrict__ out_loc,
                                             float* __restrict__ out_sc,
                                             float* __restrict__ boxes,
                                             float* __restrict__ scf,
                                             int img_base) {
    const int lane = threadIdx.x;
    const int row = blockIdx.x;
    const int fimg = blockIdx.y;
    const int n = img_base + fimg;

    float acc[56];
#pragma unroll
    for (int i = 0; i < 56; i++) acc[i] = 0.f;

    for (int ci = 0; ci < 512; ++ci) {
        float f = feat[(((size_t)fimg * 512 + ci) * 64 + row) * 64 + lane];
        const float4* wp = (const float4*)(wt1 + ci * 64);
#pragma unroll
        for (int q = 0; q < 14; q++) {
            float4 w4 = wp[q];
            acc[q * 4 + 0] = fmaf(f, w4.x, acc[q * 4 + 0]);
            acc[q * 4 + 1] = fmaf(f, w4.y, acc[q * 4 + 1]);
            acc[q * 4 + 2] = fmaf(f, w4.z, acc[q * 4 + 2]);
            acc[q * 4 + 3] = fmaf(f, w4.w, acc[q * 4 + 3]);
        }
    }

    float ihf = (float)img_h[0];
    float iwf = (float)img_w[0];
    int p = row * 64 + lane;
    size_t base = (size_t)n * NANCH + (size_t)p * 9;
    float sy = 16.f * (float)row;
    float sx = 16.f * (float)lane;
    const float rat[3] = {0.5f, 1.f, 2.f};
    const float scl[3] = {8.f, 16.f, 32.f};

#pragma unroll
    for (int a = 0; a < 9; a++) {
        int rr = a / 3, s = a % 3;
        float hh = 16.f * scl[s] * sqrtf(rat[rr]);
        float wwv = 16.f * scl[s] * sqrtf(1.f / rat[rr]);
        float ab0 = 8.f - 0.5f * hh, ab1 = 8.f - 0.5f * wwv;
        float ab2 = 8.f + 0.5f * hh, ab3 = 8.f + 0.5f * wwv;
        float a0 = sy + ab0, a1c = sx + ab1, a2 = sy + ab2, a3 = sx + ab3;

        float s0 = acc[a * 2 + 0] + sb[a * 2 + 0];
        float s1 = acc[a * 2 + 1] + sb[a * 2 + 1];
        ((float2*)out_sc)[base + a] = make_float2(s0, s1);
        float m = fmaxf(s0, s1);
        float e0 = expf(s0 - m), e1 = expf(s1 - m);
        float fg = e1 / (e0 + e1);

        float dy = acc[18 + a * 4 + 0] + lb[a * 4 + 0];
        float dx = acc[18 + a * 4 + 1] + lb[a * 4 + 1];
        float dh = acc[18 + a * 4 + 2] + lb[a * 4 + 2];
        float dw = acc[18 + a * 4 + 3] + lb[a * 4 + 3];
        ((float4*)out_loc)[base + a] = make_float4(dy, dx, dh, dw);

        float h_ = a2 - a0, w_ = a3 - a1c;
        float cy = a0 + 0.5f * h_, cx = a1c + 0.5f * w_;
        float ncy = dy * h_ + cy, ncx = dx * w_ + cx;
        float nh = expf(dh) * h_, nw = expf(dw) * w_;
        float y1 = ncy - 0.5f * nh, x1 = ncx - 0.5f * nw;
        float y2 = ncy + 0.5f * nh, x2 = ncx + 0.5f * nw;
        y1 = fminf(fmaxf(y1, 0.f), ihf);
        x1 = fminf(fmaxf(x1, 0.f), iwf);
        y2 = fminf(fmaxf(y2, 0.f), ihf);
        x2 = fminf(fmaxf(x2, 0.f), iwf);
        float hs = y2 - y1, wsz = x2 - x1;
        bool valid = (hs >= 16.f) && (wsz >= 16.f);
        ((float4*)boxes)[base + a] = make_float4(y1, x1, y2, x2);
        scf[base + a] = valid ? fg : NEG_INF_F;
    }
}

// ---------------- radix select: exact rank-6000 value per batch ----------------
__global__ __launch_bounds__(1024) void radix_k(const float* __restrict__ scf, u32* __restrict__ uT) {
    const int b = blockIdx.x;
    const int tid = threadIdx.x;
    const float* s = scf + (size_t)b * NANCH;
    __shared__ u32 hist[256];
    __shared__ u32 sel_prefix;
    __shared__ int sel_rank;
    if (tid == 0) { sel_prefix = 0u; sel_rank = NPRE; }
    __syncthreads();
    for (int p = 3; p >= 0; --p) {
        for (int i = tid; i < 256; i += 1024) hist[i] = 0u;
        __syncthreads();
        u32 prefix = sel_prefix;
        u32 highmask = (p == 3) ? 0u : (0xFFFFFFFFu << ((p + 1) * 8));
        for (int i = tid; i < NANCH; i += 1024) {
            u32 u = fsort(s[i]);
            if ((u & highmask) == prefix)
                atomicAdd(&hist[(u >> (p * 8)) & 255], 1u);
        }
        __syncthreads();
        if (tid == 0) {
            int r = sel_rank;
            u32 accum = 0;
            int bsel = 0;
            for (int bb = 255; bb >= 0; --bb) {
                accum += hist[bb];
                if ((int)accum >= r) {
                    bsel = bb;
                    sel_rank = r - (int)(accum - hist[bb]);
                    break;
                }
            }
            sel_prefix = prefix | ((u32)bsel << (p * 8));
        }
        __syncthreads();
    }
    if (tid == 0) uT[b] = sel_prefix;
}

// ---------------- compact: gather valid entries with score >= threshold ----------------
__global__ void compact_k(const float* __restrict__ scf, const u32* __restrict__ uT,
                          u32* __restrict__ cnt, u32* __restrict__ cidx) {
    int b = blockIdx.y;
    int i = blockIdx.x * 256 + threadIdx.x;
    float s = scf[(size_t)b * NANCH + i];
    u32 u = fsort(s);
    if (u >= uT[b] && s > -5e29f) {
        u32 p = atomicAdd(&cnt[b], 1u);
        if (p < CAP) cidx[(size_t)b * CAP + p] = (u32)i;
    }
}

// ---------------- sort: per-batch bitonic desc over keys, truncate to 6000, gather boxes
__global__ __launch_bounds__(1024) void sort_k(const float* __restrict__ scf,
                                               const float* __restrict__ boxes,
                                               u32* __restrict__ cnt,
                                               const u32* __restrict__ cidx,
                                               float4* __restrict__ sbox) {
    __shared__ u64 sk[8192];   // 64 KB
    const int b = blockIdx.x;
    const int tid = threadIdx.x;
    int count = (int)cnt[b];
    if (count > CAP) count = CAP;

    for (int i = tid; i < 8192; i += 1024) {
        u64 key = 0ull;
        if (i < count) {
            u32 idx = cidx[(size_t)b * CAP + i];
            u32 u = fsort(scf[(size_t)b * NANCH + idx]);
            key = ((u64)u << 32) | (u64)(0xFFFFFFFFu - idx);
        }
        sk[i] = key;
    }

    for (int k = 2; k <= 8192; k <<= 1) {
        for (int j = k >> 1; j > 0; j >>= 1) {
            __syncthreads();
            for (int i = tid; i < 8192; i += 1024) {
                int p = i ^ j;
                if (p > i) {
                    bool up = (i & k) == 0;     // descending overall
                    u64 a = sk[i], c = sk[p];
                    bool sw = up ? (a < c) : (a > c);
                    if (sw) { sk[i] = c; sk[p] = a; }
                }
            }
        }
    }
    __syncthreads();

    int S = count < NKEEP ? count : NKEEP;
    if (tid == 0) cnt[4 + b] = (u32)S;
    const float4* Bx = (const float4*)boxes;
    for (int i = tid; i < S; i += 1024) {
        u32 idx = 0xFFFFFFFFu - (u32)(sk[i] & 0xFFFFFFFFull);
        sbox[(size_t)b * CAP + i] = Bx[(size_t)b * NANCH + idx];
    }
}

// ---------------- mask build: bit (j,k) = IoU(sorted_j, sorted_k) > 0.7 ----------------
__global__ __launch_bounds__(256) void mask_k(const float4* __restrict__ sbox,
                                              const u32* __restrict__ cnt,
                                              u32* __restrict__ mask) {
    __shared__ float4 rb[64];
    __shared__ float ra[64];
    const int tile = blockIdx.x;
    const int b = blockIdx.y;
    const int tid = threadIdx.x;
    const int lane = tid & 63;
    const int wv = tid >> 6;
    const int r0 = tile * 64;

    if (tid < 64) {
        float4 v = sbox[(size_t)b * CAP + (r0 + tid)];
        rb[tid] = v;
        ra[tid] = (v.z - v.x) * (v.w - v.y);
    }
    __syncthreads();

    for (int chunk = (tile >> 2); chunk < 24; ++chunk) {
        int c = chunk * 256 + tid;
        float4 cb = sbox[(size_t)b * CAP + c];
        float a2 = (cb.z - cb.x) * (cb.w - cb.y);
        u64 mine = 0ull;
#pragma unroll 4
        for (int r = 0; r < 64; ++r) {
            float4 rr = rb[r];
            float ty = fmaxf(rr.x, cb.x);
            float tx = fmaxf(rr.y, cb.y);
            float by = fminf(rr.z, cb.z);
            float bx = fminf(rr.w, cb.w);
            float ih = fmaxf(by - ty, 0.f);
            float iw = fmaxf(bx - tx, 0.f);
            float inter = ih * iw;
            float iou = inter / fmaxf(ra[r] + a2 - inter, 1e-6f);
            u64 bal = __ballot(iou > 0.7f);
            if (lane == r) mine = bal;
        }
        int row = r0 + lane;
        u64* dst = (u64*)(mask + ((size_t)b * MROWS + row) * MW);
        dst[chunk * 4 + wv] = mine;
    }
}

// ---------------- scan: serial greedy (wave 0) + L2-warmer waves 1..15 ----------------
// Selections are monotone in sorted index, so warmers stream rows in a sliding
// window ahead of the consumer's published cursor; consumer reads global (L2-hot).
__global__ __launch_bounds__(1024) void scan_k(const u32* __restrict__ mask,
                                               const float4* __restrict__ sbox,
                                               const u32* __restrict__ cnt,
                                               u32* __restrict__ sink,
                                               float4* __restrict__ out_rois) {
    const int b = blockIdx.x;
    const int tid = threadIdx.x;
    const int wv = tid >> 6;
    const int lane = tid & 63;
    const int S = (int)cnt[4 + b];

    __shared__ int keep[NPOST];
    __shared__ int posS;
    volatile int* vpos = &posS;
    if (tid == 0) *vpos = 0;
    __syncthreads();

    const u32* mbase = mask + (size_t)b * MROWS * MW;

    if (wv == 0) {
        u32 a0, a1, a2v;
        {
            int w;
            w = lane;       a0  = (w * 32 + 32 <= S) ? 0xFFFFFFFFu : ((w * 32 < S) ? ((1u << (S - w * 32)) - 1u) : 0u);
            w = 64 + lane;  a1  = (w * 32 + 32 <= S) ? 0xFFFFFFFFu : ((w * 32 < S) ? ((1u << (S - w * 32)) - 1u) : 0u);
            w = 128 + lane; a2v = (w * 32 + 32 <= S) ? 0xFFFFFFFFu : ((w * 32 < S) ? ((1u << (S - w * 32)) - 1u) : 0u);
        }

        int it = 0;
        while (it < NPOST) {
            int j;
            u64 b0 = __ballot(a0 != 0u);
            if (b0) {
                int L = __builtin_ctzll(b0);
                int cv = (lane << 5) + ctz32(a0);
                j = __shfl(cv, L);
            } else {
                u64 b1 = __ballot(a1 != 0u);
                if (b1) {
                    int L = __builtin_ctzll(b1);
                    int cv = ((64 + lane) << 5) + ctz32(a1);
                    j = __shfl(cv, L);
                } else {
                    u64 b2 = __ballot(a2v != 0u);
                    if (!b2) break;
                    int L = __builtin_ctzll(b2);
                    int cv = ((128 + lane) << 5) + ctz32(a2v);
                    j = __shfl(cv, L);
                }
            }
            if (lane == 0) { keep[it] = j; *vpos = j; }
            ++it;

            int wj = j >> 5;
            u32 bit = 1u << (j & 31);
            if (wj == lane) a0 &= ~bit;
            else if (wj == 64 + lane) a1 &= ~bit;
            else if (wj == 128 + lane) a2v &= ~bit;

            const u32* row = mbase + (size_t)j * MW;
            u32 m0 = row[lane];
            u32 m1 = row[64 + lane];
            u32 m2 = row[128 + lane];
            a0 &= ~m0; a1 &= ~m1; a2v &= ~m2;
        }

        if (lane == 0) *vpos = (1 << 28);    // release warmers

        int total = it;
        for (int i = lane; i < NPOST; i += 64) {
            float4 v = make_float4(0.f, 0.f, 0.f, 0.f);
            if (i < total) v = sbox[(size_t)b * CAP + keep[i]];
            out_rois[(size_t)b * NPOST + i] = v;
        }
    } else {
        // warmer: stream rows (wv-1) + 15k, staying within window of the cursor
        u32 dummy = 0u;
        const int W = 2048;
        for (int r = wv - 1; r < MROWS; r += 15) {
            int sp = 0;
            while (*vpos + W <= r && sp < 65536) { __builtin_amdgcn_s_sleep(2); ++sp; }
            if (*vpos >= (1 << 27)) break;
            const u32* row = mbase + (size_t)r * MW;
            dummy += row[lane] + row[64 + lane] + row[128 + lane];
        }
        if (dummy == 0xDEADBEEFu) sink[b] = dummy;   // keep loads alive; harmless scratch
    }
}

// ---------------- launch ----------------
extern "C" void kernel_launch(void* const* d_in, const int* in_sizes, int n_in,
                              void* d_out, int out_size, void* d_ws, size_t ws_size,
                              hipStream_t stream) {
    const float* x  = (const float*)d_in[0];
    const float* w1 = (const float*)d_in[1];
    const float* b1 = (const float*)d_in[2];
    const float* sw = (const float*)d_in[3];
    const float* sb = (const float*)d_in[4];
    const float* lw = (const float*)d_in[5];
    const float* lb = (const float*)d_in[6];
    const int* ih   = (const int*)d_in[7];
    const int* iw   = (const int*)d_in[8];
    float* out = (float*)d_out;

    char* ws = (char*)d_ws;
    const size_t FEAT_OFF = 14286848;                 // Wp = [0, 14155776)
    const size_t NEED_BIG = 51413504;                 // big layout total bytes
    const bool big = (ws_size >= NEED_BIG);

    ushort_t* Wp  = (ushort_t*)(ws);
    float* feat   = (float*)(ws + FEAT_OFF);
    u32* mask     = (u32*)(ws);                       // 18481152 B (overlays dead Wp/feat)
    const size_t RB = big ? (FEAT_OFF + 33554432) : (FEAT_OFF + 16777216);
    float* wt1    = (float*)(ws + RB);                // 131072
    float* boxes  = (float*)(ws + RB + 131072);       // 2359296
    float* scf    = (float*)(ws + RB + 2490368);      // 589824
    u32* uT       = (u32*)(ws + RB + 3080192);
    u32* cnt      = (u32*)(ws + RB + 3080448);
    u32* cidx     = (u32*)(ws + RB + 3080704);        // 98304 (dead after sort -> sink)
    float4* sbox  = (float4*)(ws + RB + 3179008);     // 393216 -> end RB+3572224

    float* out_loc = out;                  // 589824 floats
    float* out_sc  = out + 589824;         // 294912 floats
    float4* out_roi = (float4*)(out + 884736);  // 4800 floats
    float* out_anc = out + 889536;         // 147456 floats

    hipLaunchKernelGGL(setup_k, dim3(401), dim3(256), 0, stream, w1, sw, lw, Wp, wt1, out_anc, cnt);

    if (big) {
        hipLaunchKernelGGL(conv_mfma_k, dim3(512), dim3(256), 0, stream, x, Wp, b1, feat, 0);
        hipLaunchKernelGGL(head_k, dim3(64, 4), dim3(64), 0, stream, feat, wt1, sb, lb, ih, iw,
                           out_loc, out_sc, boxes, scf, 0);
    } else {
        for (int pass = 0; pass < 2; ++pass) {
            hipLaunchKernelGGL(conv_mfma_k, dim3(256), dim3(256), 0, stream, x, Wp, b1, feat, pass * 2);
            hipLaunchKernelGGL(head_k, dim3(64, 2), dim3(64), 0, stream, feat, wt1, sb, lb, ih, iw,
                               out_loc, out_sc, boxes, scf, pass * 2);
        }
    }

    hipLaunchKernelGGL(radix_k, dim3(4), dim3(1024), 0, stream, scf, uT);
    hipLaunchKernelGGL(compact_k, dim3(144, 4), dim3(256), 0, stream, scf, uT, cnt, cidx);
    hipLaunchKernelGGL(sort_k, dim3(4), dim3(1024), 0, stream, scf, boxes, cnt, cidx, sbox);
    hipLaunchKernelGGL(mask_k, dim3(94, 4), dim3(256), 0, stream, sbox, cnt, mask);
    hipLaunchKernelGGL(scan_k, dim3(4), dim3(1024), 0, stream, mask, sbox, cnt, cidx, out_roi);
}